// Round 6
// baseline (452.072 us; speedup 1.0000x reference)
//
#include <hip/hip_runtime.h>
#include <hip/hip_bf16.h>

typedef __hip_bfloat16 bf16;
typedef __attribute__((ext_vector_type(8))) short short8;   // 8 bf16 frag
typedef __attribute__((ext_vector_type(4))) float floatx4;  // MFMA C/D frag

#define HDIM 128
#define NCANON 27

__device__ __forceinline__ float b2f(bf16 v) { return __bfloat162float(v); }
__device__ __forceinline__ float s2f(short s) {
  return __uint_as_float(((unsigned int)(unsigned short)s) << 16);
}
__device__ __forceinline__ short f2s(float f) {
  return (short)__bfloat16_as_ushort(__float2bfloat16(f));
}

struct CanonDesc {
  const void* src[NCANON];
  int prefix[NCANON + 1];
};

// ---- canon + inlined dtype detect + zero-fill of m_node/counts/cursor (tail blocks)
__global__ void canon_kernel(CanonDesc d, const unsigned short* __restrict__ xraw,
                             int* __restrict__ flagOut, bf16* __restrict__ out, int total,
                             int canonBlocks, uint4* __restrict__ zbase, int zquads) {
  int tid = threadIdx.x;
  if (blockIdx.x >= canonBlocks) {
    int i = (blockIdx.x - canonBlocks) * 256 + tid;
    if (i < zquads) { uint4 z = {0u, 0u, 0u, 0u}; zbase[i] = z; }
    return;
  }
  __shared__ int sflag;
  if (tid < 64) {
    unsigned short u = xraw[2 * tid];
    int e = (u >> 7) & 0xFF;
    int ok = (u == 0) || (e >= 100 && e <= 140);
    unsigned long long m = __ballot(ok);
    if (tid == 0) sflag = (__popcll(m) >= 48) ? 1 : 0;
  }
  __syncthreads();
  int isBf = sflag;
  if (blockIdx.x == 0 && tid == 0) flagOut[0] = isBf;
  int t = blockIdx.x * 256 + tid;
  if (t >= total) return;
  int lo = 0, hi = NCANON;
  while (lo + 1 < hi) { int mid = (lo + hi) >> 1; if (d.prefix[mid] <= t) lo = mid; else hi = mid; }
  int off = t - d.prefix[lo];
  out[t] = isBf ? ((const bf16*)d.src[lo])[off]
                : __float2bfloat16(((const float*)d.src[lo])[off]);
}

// ---------------- hist (dst histogram) + tsort (type counting sort), one dispatch
__global__ void __launch_bounds__(1024) hist_tsort_kernel(
    const int* __restrict__ dst, int* __restrict__ cnt, int E, int hb,
    const int* __restrict__ types, int* __restrict__ ts, int* __restrict__ perm, int n) {
  if (blockIdx.x < hb) {
    int e = blockIdx.x * 1024 + threadIdx.x;
    if (e < E) atomicAdd(&cnt[dst[e]], 1);
    return;
  }
  // ---- tsort body (single block, 1024 threads)
  __shared__ int wc[16][3];
  __shared__ int base[3];
  int tid = threadIdx.x, lane = tid & 63, wave = tid >> 6;
  int c0 = 0, c1 = 0, c2 = 0;
  for (int i = tid; i < n; i += 1024) {
    int t = types[i];
    c0 += (t == 0); c1 += (t == 1); c2 += (t == 2);
  }
  #pragma unroll
  for (int d = 32; d; d >>= 1) {
    c0 += __shfl_down(c0, d); c1 += __shfl_down(c1, d); c2 += __shfl_down(c2, d);
  }
  if (lane == 0) { wc[wave][0] = c0; wc[wave][1] = c1; wc[wave][2] = c2; }
  __syncthreads();
  if (tid == 0) {
    int t0 = 0, t1 = 0;
    for (int w = 0; w < 16; w++) { t0 += wc[w][0]; t1 += wc[w][1]; }
    ts[0] = 0; ts[1] = t0; ts[2] = t0 + t1; ts[3] = n;
    base[0] = 0; base[1] = t0; base[2] = t0 + t1;
  }
  __syncthreads();
  for (int i0 = 0; i0 < n; i0 += 1024) {
    int i = i0 + tid;
    int t = (i < n) ? types[i] : -1;
    unsigned long long m0 = __ballot(t == 0);
    unsigned long long m1 = __ballot(t == 1);
    unsigned long long m2 = __ballot(t == 2);
    if (lane == 0) { wc[wave][0] = __popcll(m0); wc[wave][1] = __popcll(m1); wc[wave][2] = __popcll(m2); }
    __syncthreads();
    if (i < n) {
      unsigned long long mt = (t == 0) ? m0 : ((t == 1) ? m1 : m2);
      unsigned long long below = (lane == 0) ? 0ull : ((1ull << lane) - 1ull);
      int r = __popcll(mt & below);
      int woff = 0;
      for (int w = 0; w < wave; w++) woff += wc[w][t];
      perm[base[t] + woff + r] = i;
    }
    __syncthreads();
    if (tid == 0) {
      int a0 = 0, a1 = 0, a2 = 0;
      for (int w = 0; w < 16; w++) { a0 += wc[w][0]; a1 += wc[w][1]; a2 += wc[w][2]; }
      base[0] += a0; base[1] += a1; base[2] += a2;
    }
    __syncthreads();
  }
}

__global__ void scan1_kernel(const int* __restrict__ cnt, int* __restrict__ bsum, int n) {
  int tid = threadIdx.x, lane = tid & 63, wave = tid >> 6;
  int i = blockIdx.x * 256 + tid;
  int v = (i < n) ? cnt[i] : 0;
  #pragma unroll
  for (int d = 32; d; d >>= 1) v += __shfl_down(v, d);
  __shared__ int ws[4];
  if (lane == 0) ws[wave] = v;
  __syncthreads();
  if (tid == 0) bsum[blockIdx.x] = ws[0] + ws[1] + ws[2] + ws[3];
}

__global__ void scan2_kernel(int* __restrict__ bsum, int nb) {   // nb <= 128; 64 threads
  int lane = threadIdx.x;
  int a0 = (lane < nb) ? bsum[lane] : 0;
  int b0 = (64 + lane < nb) ? bsum[64 + lane] : 0;
  int a = a0, b = b0;
  #pragma unroll
  for (int d = 1; d < 64; d <<= 1) { int t = __shfl_up(a, d); if (lane >= d) a += t; }
  int totA = __shfl(a, 63);
  #pragma unroll
  for (int d = 1; d < 64; d <<= 1) { int t = __shfl_up(b, d); if (lane >= d) b += t; }
  int totB = __shfl(b, 63);
  if (lane < nb) bsum[lane] = a - a0;
  if (64 + lane < nb) bsum[64 + lane] = b - b0 + totA;
  if (lane == 0) bsum[nb] = totA + totB;
}

__global__ void scan3_kernel(const int* __restrict__ cnt, const int* __restrict__ bsum,
                             int* __restrict__ row_start, int n, int nb) {
  __shared__ int sh[256];
  int tid = threadIdx.x;
  int i = blockIdx.x * 256 + tid;
  int v = (i < n) ? cnt[i] : 0;
  sh[tid] = v;
  __syncthreads();
  #pragma unroll
  for (int off = 1; off < 256; off <<= 1) {
    int t = (tid >= off) ? sh[tid - off] : 0;
    __syncthreads();
    sh[tid] += t;
    __syncthreads();
  }
  if (i < n) row_start[i] = bsum[blockIdx.x] + sh[tid] - v;
  if (blockIdx.x == 0 && tid == 0) row_start[n] = bsum[nb];
}

// scatter: permutes edge_attr into dst-sorted order too
__global__ void scatter_kernel(const int* __restrict__ src, const int* __restrict__ dst,
                               const int* __restrict__ row_start, int* __restrict__ cursor,
                               const bf16* __restrict__ ea, bf16* __restrict__ eaS,
                               int* __restrict__ srcS, int* __restrict__ dstS, int E) {
  int e = blockIdx.x * 256 + threadIdx.x;
  if (e < E) {
    int d = dst[e];
    int pos = row_start[d] + atomicAdd(&cursor[d], 1);
    srcS[pos] = src[e];
    dstS[pos] = d;
    *(uint2*)(eaS + (size_t)pos * 4) = *(const uint2*)(ea + (size_t)e * 4);
  }
}

// -------------------------------------------------- fused weight pre-pack (B-frag order)
struct PackJob { const bf16* src; bf16* dst; int Ksrc; int KS; int srcCols; };
struct PackJobs { PackJob j[40]; };

__global__ void pack_all_kernel(PackJobs J) {
  PackJob job = J.j[blockIdx.y];
  int idx = blockIdx.x * 256 + threadIdx.x;
  int total = 8 * job.KS * 64;
  if (idx >= total) return;
  int lane = idx & 63;
  int ks = (idx >> 6) % job.KS;
  int ct = idx / (64 * job.KS);
  bf16* o = job.dst + (size_t)idx * 8;
  int ncol = ct * 16 + (lane & 15);
  int kb = ks * 32 + ((lane >> 4) & 3) * 8;
  #pragma unroll
  for (int jj = 0; jj < 8; jj++) {
    int k = kb + jj;
    o[jj] = (k < job.Ksrc && ncol < job.srcCols)
              ? job.src[(size_t)k * job.srcCols + ncol] : __float2bfloat16(0.f);
  }
}

// ----------------------- edge-update + fused dst-segment aggregation
// Round-3 best config: BM=64, 512 threads, 8 waves x 1 col-tile, scalar scan.
template<bool WRITE_HE>
__global__ void __launch_bounds__(512) eu_kernel(
    const bf16* __restrict__ he, const bf16* __restrict__ ysrc, const bf16* __restrict__ ydst,
    const int* __restrict__ srcS, const int* __restrict__ dstS,
    const bf16* __restrict__ W1p, const bf16* __restrict__ b1v,
    const bf16* __restrict__ W2p, const bf16* __restrict__ b2v,
    bf16* __restrict__ outp, float* __restrict__ mnode, int M) {
  constexpr int BM = 64, RT = 4, SK = 272;
  __shared__ bf16 Zt[BM * SK];
  __shared__ int dstLds[BM];
  const int tid = threadIdx.x;
  const int lane = tid & 63, wave = tid >> 6, colq = lane & 15, quad = lane >> 4;
  // XCD-aware bijective swizzle (dst-sorted edges -> L2 locality per XCD)
  const int nwg = gridDim.x, bid = blockIdx.x;
  const int qq = nwg >> 3, rr = nwg & 7;
  const int xcd = bid & 7, bidx = bid >> 3;
  const int blk = (xcd < rr ? xcd * (qq + 1) : rr * (qq + 1) + (xcd - rr) * qq) + bidx;
  const int row0 = blk * BM;
  {
    int row = tid >> 3, sub = tid & 7;
    int gr = row0 + row;
    bool ok = gr < M;
    int g0 = ok ? srcS[gr] : 0;
    int g1 = ok ? dstS[gr] : 0;
    if (sub == 0) dstLds[row] = ok ? g1 : -1;
    #pragma unroll
    for (int j = 0; j < 4; j++) {
      int c = j * 8 + sub;
      int part = c >> 4, seg = c & 15;
      if (part == 0) {
        short8 o = {0, 0, 0, 0, 0, 0, 0, 0};
        if (ok) {
          short8 a = *(const short8*)(ysrc + (size_t)g0 * HDIM + seg * 8);
          short8 b = *(const short8*)(ydst + (size_t)g1 * HDIM + seg * 8);
          #pragma unroll
          for (int k = 0; k < 8; k++) o[k] = f2s(s2f(a[k]) + s2f(b[k]));
        }
        *(short8*)(&Zt[row * SK + seg * 8]) = o;
      } else {
        uint4 v = {0u, 0u, 0u, 0u};
        if (ok) v = *(const uint4*)(he + (size_t)gr * HDIM + seg * 8);
        *(uint4*)(&Zt[row * SK + 128 + seg * 8]) = v;
      }
    }
  }
  __syncthreads();

  floatx4 acc[RT];
  #pragma unroll
  for (int rt = 0; rt < RT; rt++) acc[rt] = (floatx4){0.f, 0.f, 0.f, 0.f};
  #pragma unroll
  for (int ks = 0; ks < 4; ks++) {
    short8 bfr = *(const short8*)(W1p + (((size_t)wave * 4 + ks) * 64 + lane) * 8);
    #pragma unroll
    for (int rt = 0; rt < RT; rt++) {
      short8 a = *(const short8*)(&Zt[(rt * 16 + colq) * SK + 128 + ks * 32 + quad * 8]);
      acc[rt] = __builtin_amdgcn_mfma_f32_16x16x32_bf16(a, bfr, acc[rt], 0, 0, 0);
    }
  }
  {
    int col = wave * 16 + colq;
    float bv = b2f(b1v[col]);
    #pragma unroll
    for (int rt = 0; rt < RT; rt++)
      #pragma unroll
      for (int r = 0; r < 4; r++) {
        int lrow = rt * 16 + quad * 4 + r;
        float v = acc[rt][r] + bv + b2f(Zt[lrow * SK + col]);
        Zt[lrow * SK + col] = __float2bfloat16(fmaxf(v, 0.f));
      }
  }
  __syncthreads();

  #pragma unroll
  for (int rt = 0; rt < RT; rt++) acc[rt] = (floatx4){0.f, 0.f, 0.f, 0.f};
  #pragma unroll
  for (int ks = 0; ks < 4; ks++) {
    short8 bfr = *(const short8*)(W2p + (((size_t)wave * 4 + ks) * 64 + lane) * 8);
    #pragma unroll
    for (int rt = 0; rt < RT; rt++) {
      short8 a = *(const short8*)(&Zt[(rt * 16 + colq) * SK + ks * 32 + quad * 8]);
      acc[rt] = __builtin_amdgcn_mfma_f32_16x16x32_bf16(a, bfr, acc[rt], 0, 0, 0);
    }
  }
  {
    int col = wave * 16 + colq;
    float bv = b2f(b2v[col]);
    #pragma unroll
    for (int rt = 0; rt < RT; rt++)
      #pragma unroll
      for (int r = 0; r < 4; r++) {
        int lrow = rt * 16 + quad * 4 + r;
        float v = acc[rt][r] + bv + b2f(Zt[lrow * SK + 128 + col]);
        Zt[lrow * SK + 128 + col] = __float2bfloat16(v);
      }
  }
  __syncthreads();

  if (WRITE_HE) {
    #pragma unroll
    for (int i = tid; i < BM * 16; i += 512) {
      int row = i >> 4, seg = i & 15;
      int gr = row0 + row;
      if (gr < M)
        *(uint4*)(outp + (size_t)gr * HDIM + seg * 8) = *(const uint4*)(&Zt[row * SK + 128 + seg * 8]);
    }
  }
  {
    int col = tid & 127;
    int q4 = tid >> 7;                  // 0..3: quarter of 16 rows
    int rbeg = q4 * 16, rend = rbeg + 16;
    float s = 0.f;
    int runDst = dstLds[rbeg];
    bool touchStart = true;
    for (int r = rbeg; r < rend; r++) {
      int d = dstLds[r];
      if (d != runDst) {
        if (runDst >= 0) {
          float* mp = &mnode[(size_t)runDst * HDIM + col];
          if (touchStart) atomicAdd(mp, s); else *mp = s;
        }
        runDst = d; s = 0.f; touchStart = false;
      }
      s += b2f(Zt[r * SK + 128 + col]);
    }
    if (runDst >= 0) atomicAdd(&mnode[(size_t)runDst * HDIM + col], s);
  }
}

// ----------------------- fused node update + fusion MLP (+ next-layer Y emit)
// 512 threads, 2x4 wave grid (round-5 win): halves the serial per-block latency at
// 1.2 blocks/CU grid quantization.
__global__ void __launch_bounds__(512) node_kernel(
    const bf16* __restrict__ h_nodes, float* __restrict__ mnode,
    const bf16* __restrict__ nuW1, const bf16* __restrict__ nuB1,
    const bf16* __restrict__ nuW2, const bf16* __restrict__ nuB2,
    const bf16* __restrict__ fuW1, const bf16* __restrict__ fuB1,
    const bf16* __restrict__ fuW2, const bf16* __restrict__ fuB2,
    const bf16* __restrict__ yW1a, const bf16* __restrict__ yW1b,
    bf16* __restrict__ ysA, bf16* __restrict__ ysB,
    bf16* __restrict__ outp, int M) {
  constexpr int BM = 64, SK = 272;
  __shared__ bf16 Zt[BM * SK];
  const int tid = threadIdx.x;
  const int lane = tid & 63, wave = tid >> 6, colq = lane & 15, quad = lane >> 4;
  const int wr = wave >> 2, wc = wave & 3;   // 2 row-groups x 4 col-groups
  const int row0 = blockIdx.x * BM;
  {
    int row = tid >> 3, sub = tid & 7;
    int gr = row0 + row;
    bool ok = gr < M;
    float4 z4 = {0.f, 0.f, 0.f, 0.f};
    #pragma unroll
    for (int j = 0; j < 4; j++) {
      int c = j * 8 + sub;
      int part = c >> 4, seg = c & 15;
      if (part == 0) {
        uint4 v = {0u, 0u, 0u, 0u};
        if (ok) v = *(const uint4*)(h_nodes + (size_t)gr * HDIM + seg * 8);
        *(uint4*)(&Zt[row * SK + seg * 8]) = v;
      } else {
        short8 o = {0, 0, 0, 0, 0, 0, 0, 0};
        if (ok) {
          float* mp = mnode + (size_t)gr * HDIM + seg * 8;
          #pragma unroll
          for (int k = 0; k < 8; k++) o[k] = f2s(mp[k]);
          if (yW1a) { *(float4*)(mp) = z4; *(float4*)(mp + 4) = z4; }
        }
        *(short8*)(&Zt[row * SK + 128 + seg * 8]) = o;
      }
    }
  }
  __syncthreads();

  floatx4 acc[2][2];
  // ---- GEMM1: nuW1, K=256
  #pragma unroll
  for (int rt = 0; rt < 2; rt++)
    #pragma unroll
    for (int c = 0; c < 2; c++) acc[rt][c] = (floatx4){0.f, 0.f, 0.f, 0.f};
  #pragma unroll
  for (int ks = 0; ks < 8; ks++) {
    short8 bfr0 = *(const short8*)(nuW1 + (((size_t)(wc * 2 + 0) * 8 + ks) * 64 + lane) * 8);
    short8 bfr1 = *(const short8*)(nuW1 + (((size_t)(wc * 2 + 1) * 8 + ks) * 64 + lane) * 8);
    #pragma unroll
    for (int rt = 0; rt < 2; rt++) {
      short8 a = *(const short8*)(&Zt[(wr * 32 + rt * 16 + colq) * SK + ks * 32 + quad * 8]);
      acc[rt][0] = __builtin_amdgcn_mfma_f32_16x16x32_bf16(a, bfr0, acc[rt][0], 0, 0, 0);
      acc[rt][1] = __builtin_amdgcn_mfma_f32_16x16x32_bf16(a, bfr1, acc[rt][1], 0, 0, 0);
    }
  }
  __syncthreads();
  #pragma unroll
  for (int c = 0; c < 2; c++) {
    int col = wc * 32 + c * 16 + colq;
    float bv = b2f(nuB1[col]);
    #pragma unroll
    for (int rt = 0; rt < 2; rt++)
      #pragma unroll
      for (int r = 0; r < 4; r++)
        Zt[(wr * 32 + rt * 16 + quad * 4 + r) * SK + 128 + col] =
            __float2bfloat16(fmaxf(acc[rt][c][r] + bv, 0.f));
  }
  __syncthreads();

  // ---- GEMM2: nuW2 (reads hidden at +128), residual h from Zt[0..127]
  #pragma unroll
  for (int rt = 0; rt < 2; rt++)
    #pragma unroll
    for (int c = 0; c < 2; c++) acc[rt][c] = (floatx4){0.f, 0.f, 0.f, 0.f};
  #pragma unroll
  for (int ks = 0; ks < 4; ks++) {
    short8 bfr0 = *(const short8*)(nuW2 + (((size_t)(wc * 2 + 0) * 4 + ks) * 64 + lane) * 8);
    short8 bfr1 = *(const short8*)(nuW2 + (((size_t)(wc * 2 + 1) * 4 + ks) * 64 + lane) * 8);
    #pragma unroll
    for (int rt = 0; rt < 2; rt++) {
      short8 a = *(const short8*)(&Zt[(wr * 32 + rt * 16 + colq) * SK + 128 + ks * 32 + quad * 8]);
      acc[rt][0] = __builtin_amdgcn_mfma_f32_16x16x32_bf16(a, bfr0, acc[rt][0], 0, 0, 0);
      acc[rt][1] = __builtin_amdgcn_mfma_f32_16x16x32_bf16(a, bfr1, acc[rt][1], 0, 0, 0);
    }
  }
  #pragma unroll
  for (int c = 0; c < 2; c++) {
    int col = wc * 32 + c * 16 + colq;
    float bv = b2f(nuB2[col]);
    #pragma unroll
    for (int rt = 0; rt < 2; rt++)
      #pragma unroll
      for (int r = 0; r < 4; r++) {
        int lrow = wr * 32 + rt * 16 + quad * 4 + r;
        float v = acc[rt][c][r] + bv + b2f(Zt[lrow * SK + col]);
        Zt[lrow * SK + col] = __float2bfloat16(v);
      }
  }
  __syncthreads();

  // ---- GEMM3: fuW1 (reads local at 0..127), hidden to +128
  #pragma unroll
  for (int rt = 0; rt < 2; rt++)
    #pragma unroll
    for (int c = 0; c < 2; c++) acc[rt][c] = (floatx4){0.f, 0.f, 0.f, 0.f};
  #pragma unroll
  for (int ks = 0; ks < 4; ks++) {
    short8 bfr0 = *(const short8*)(fuW1 + (((size_t)(wc * 2 + 0) * 4 + ks) * 64 + lane) * 8);
    short8 bfr1 = *(const short8*)(fuW1 + (((size_t)(wc * 2 + 1) * 4 + ks) * 64 + lane) * 8);
    #pragma unroll
    for (int rt = 0; rt < 2; rt++) {
      short8 a = *(const short8*)(&Zt[(wr * 32 + rt * 16 + colq) * SK + ks * 32 + quad * 8]);
      acc[rt][0] = __builtin_amdgcn_mfma_f32_16x16x32_bf16(a, bfr0, acc[rt][0], 0, 0, 0);
      acc[rt][1] = __builtin_amdgcn_mfma_f32_16x16x32_bf16(a, bfr1, acc[rt][1], 0, 0, 0);
    }
  }
  #pragma unroll
  for (int c = 0; c < 2; c++) {
    int col = wc * 32 + c * 16 + colq;
    float bv = b2f(fuB1[col]);
    #pragma unroll
    for (int rt = 0; rt < 2; rt++)
      #pragma unroll
      for (int r = 0; r < 4; r++)
        Zt[(wr * 32 + rt * 16 + quad * 4 + r) * SK + 128 + col] =
            __float2bfloat16(fmaxf(acc[rt][c][r] + bv, 0.f));
  }
  __syncthreads();

  // ---- GEMM4: fuW2 (reads +128), final h to 0..127
  #pragma unroll
  for (int rt = 0; rt < 2; rt++)
    #pragma unroll
    for (int c = 0; c < 2; c++) acc[rt][c] = (floatx4){0.f, 0.f, 0.f, 0.f};
  #pragma unroll
  for (int ks = 0; ks < 4; ks++) {
    short8 bfr0 = *(const short8*)(fuW2 + (((size_t)(wc * 2 + 0) * 4 + ks) * 64 + lane) * 8);
    short8 bfr1 = *(const short8*)(fuW2 + (((size_t)(wc * 2 + 1) * 4 + ks) * 64 + lane) * 8);
    #pragma unroll
    for (int rt = 0; rt < 2; rt++) {
      short8 a = *(const short8*)(&Zt[(wr * 32 + rt * 16 + colq) * SK + 128 + ks * 32 + quad * 8]);
      acc[rt][0] = __builtin_amdgcn_mfma_f32_16x16x32_bf16(a, bfr0, acc[rt][0], 0, 0, 0);
      acc[rt][1] = __builtin_amdgcn_mfma_f32_16x16x32_bf16(a, bfr1, acc[rt][1], 0, 0, 0);
    }
  }
  #pragma unroll
  for (int c = 0; c < 2; c++) {
    int col = wc * 32 + c * 16 + colq;
    float bv = b2f(fuB2[col]);
    #pragma unroll
    for (int rt = 0; rt < 2; rt++)
      #pragma unroll
      for (int r = 0; r < 4; r++) {
        int lrow = wr * 32 + rt * 16 + quad * 4 + r;
        Zt[lrow * SK + col] = __float2bfloat16(acc[rt][c][r] + bv);
      }
  }
  __syncthreads();
  // vectorized h_nodes write from Zt[0..127]
  for (int i = tid; i < BM * 16; i += 512) {
    int row = i >> 4, seg = i & 15;
    int gr = row0 + row;
    if (gr < M)
      *(uint4*)(outp + (size_t)gr * HDIM + seg * 8) = *(const uint4*)(&Zt[row * SK + seg * 8]);
  }
  if (!yW1a) return;

  #pragma unroll
  for (int which = 0; which < 2; which++) {
    const bf16* Wp = which ? yW1b : yW1a;
    bf16* outy = which ? ysB : ysA;
    #pragma unroll
    for (int rt = 0; rt < 2; rt++)
      #pragma unroll
      for (int c = 0; c < 2; c++) acc[rt][c] = (floatx4){0.f, 0.f, 0.f, 0.f};
    #pragma unroll
    for (int ks = 0; ks < 4; ks++) {
      short8 bfr0 = *(const short8*)(Wp + (((size_t)(wc * 2 + 0) * 4 + ks) * 64 + lane) * 8);
      short8 bfr1 = *(const short8*)(Wp + (((size_t)(wc * 2 + 1) * 4 + ks) * 64 + lane) * 8);
      #pragma unroll
      for (int rt = 0; rt < 2; rt++) {
        short8 a = *(const short8*)(&Zt[(wr * 32 + rt * 16 + colq) * SK + ks * 32 + quad * 8]);
        acc[rt][0] = __builtin_amdgcn_mfma_f32_16x16x32_bf16(a, bfr0, acc[rt][0], 0, 0, 0);
        acc[rt][1] = __builtin_amdgcn_mfma_f32_16x16x32_bf16(a, bfr1, acc[rt][1], 0, 0, 0);
      }
    }
    #pragma unroll
    for (int c = 0; c < 2; c++) {
      int col = wc * 32 + c * 16 + colq;
      #pragma unroll
      for (int rt = 0; rt < 2; rt++)
        #pragma unroll
        for (int r = 0; r < 4; r++)
          Zt[(wr * 32 + rt * 16 + quad * 4 + r) * SK + 128 + col] =
              __float2bfloat16(acc[rt][c][r]);
    }
    __syncthreads();
    for (int i = tid; i < BM * 16; i += 512) {
      int row = i >> 4, seg = i & 15;
      int gr = row0 + row;
      if (gr < M)
        *(uint4*)(outy + (size_t)gr * HDIM + seg * 8) = *(const uint4*)(&Zt[row * SK + 128 + seg * 8]);
    }
    __syncthreads();
  }
}

// --------------- fused encoder (type-sorted) + edge-encoder + layer-0 Y emit
// 512 threads, 2x4 wave split (node_kernel recipe): ee occupancy 16->32 waves/CU,
// per-stage serial latency halved; enc branch absorbs the old ygemm dispatch.
__global__ void __launch_bounds__(512) encee_kernel(
    int eeBlocks, int ngrid64,
    const bf16* __restrict__ eaS,
    const bf16* __restrict__ eeW1, const bf16* __restrict__ eeB1,
    const bf16* __restrict__ eeW2, const bf16* __restrict__ eeB2,
    bf16* __restrict__ h_edges, int E,
    const bf16* __restrict__ x, const bf16* __restrict__ pe,
    const int* __restrict__ perm, const int* __restrict__ ts,
    const bf16* __restrict__ encW1, const bf16* __restrict__ encB1,
    const bf16* __restrict__ encW2, const bf16* __restrict__ encB2,
    bf16* __restrict__ h_nodes,
    const bf16* __restrict__ yW1a, const bf16* __restrict__ yW1b,
    bf16* __restrict__ ysA, bf16* __restrict__ ysB) {
  __shared__ bf16 smem[128 * 144];   // ee: Zt[128*144]; enc: Zt[64*40] + Hid[64*144]
  __shared__ int gIdx[64];
  const int tid = threadIdx.x;
  const int lane = tid & 63, wave = tid >> 6, colq = lane & 15, quad = lane >> 4;
  const int wr = wave >> 2, wc = wave & 3;   // 2 row-groups x 4 col-groups

  if (blockIdx.x < eeBlocks) {
    // ---------------- ee body: BM=128, 2x64-row groups, RT=4
    constexpr int BM = 128, RT = 4, SK = 144;
    bf16* Zt = smem;
    const int row0 = blockIdx.x * BM;
    {
      int i = tid;                      // BM*4 == 512: one uint4 per thread
      int row = i >> 2, seg = i & 3;
      int gr = row0 + row;
      uint4 val = {0u, 0u, 0u, 0u};
      if (seg == 0 && gr < E) {
        uint2 v = *(const uint2*)(eaS + (size_t)gr * 4);
        val.x = v.x; val.y = v.y;
      }
      *(uint4*)(&Zt[row * SK + seg * 8]) = val;
    }
    __syncthreads();
    floatx4 acc[RT][2];
    #pragma unroll
    for (int rt = 0; rt < RT; rt++)
      #pragma unroll
      for (int c = 0; c < 2; c++) acc[rt][c] = (floatx4){0.f, 0.f, 0.f, 0.f};
    {
      short8 bfr0 = *(const short8*)(eeW1 + (((size_t)(wc * 2 + 0)) * 64 + lane) * 8);
      short8 bfr1 = *(const short8*)(eeW1 + (((size_t)(wc * 2 + 1)) * 64 + lane) * 8);
      #pragma unroll
      for (int rt = 0; rt < RT; rt++) {
        short8 a = *(const short8*)(&Zt[(wr * 64 + rt * 16 + colq) * SK + quad * 8]);
        acc[rt][0] = __builtin_amdgcn_mfma_f32_16x16x32_bf16(a, bfr0, acc[rt][0], 0, 0, 0);
        acc[rt][1] = __builtin_amdgcn_mfma_f32_16x16x32_bf16(a, bfr1, acc[rt][1], 0, 0, 0);
      }
    }
    __syncthreads();
    #pragma unroll
    for (int c = 0; c < 2; c++) {
      int col = wc * 32 + c * 16 + colq;
      float bv = b2f(eeB1[col]);
      #pragma unroll
      for (int rt = 0; rt < RT; rt++)
        #pragma unroll
        for (int r = 0; r < 4; r++)
          Zt[(wr * 64 + rt * 16 + quad * 4 + r) * SK + col] =
              __float2bfloat16(fmaxf(acc[rt][c][r] + bv, 0.f));
    }
    __syncthreads();
    floatx4 acc2[RT][2];
    #pragma unroll
    for (int rt = 0; rt < RT; rt++)
      #pragma unroll
      for (int c = 0; c < 2; c++) acc2[rt][c] = (floatx4){0.f, 0.f, 0.f, 0.f};
    #pragma unroll
    for (int ks = 0; ks < 4; ks++) {
      short8 bfr0 = *(const short8*)(eeW2 + (((size_t)(wc * 2 + 0) * 4 + ks) * 64 + lane) * 8);
      short8 bfr1 = *(const short8*)(eeW2 + (((size_t)(wc * 2 + 1) * 4 + ks) * 64 + lane) * 8);
      #pragma unroll
      for (int rt = 0; rt < RT; rt++) {
        short8 a = *(const short8*)(&Zt[(wr * 64 + rt * 16 + colq) * SK + ks * 32 + quad * 8]);
        acc2[rt][0] = __builtin_amdgcn_mfma_f32_16x16x32_bf16(a, bfr0, acc2[rt][0], 0, 0, 0);
        acc2[rt][1] = __builtin_amdgcn_mfma_f32_16x16x32_bf16(a, bfr1, acc2[rt][1], 0, 0, 0);
      }
    }
    __syncthreads();
    #pragma unroll
    for (int c = 0; c < 2; c++) {
      int col = wc * 32 + c * 16 + colq;
      float bv = b2f(eeB2[col]);
      #pragma unroll
      for (int rt = 0; rt < RT; rt++)
        #pragma unroll
        for (int r = 0; r < 4; r++)
          Zt[(wr * 64 + rt * 16 + quad * 4 + r) * SK + col] =
              __float2bfloat16(acc2[rt][c][r] + bv);
    }
    __syncthreads();
    for (int i = tid; i < BM * 16; i += 512) {
      int row = i >> 4, seg = i & 15;
      int gr = row0 + row;
      if (gr < E)
        *(uint4*)(h_edges + (size_t)gr * HDIM + seg * 8) = *(const uint4*)(&Zt[row * SK + seg * 8]);
    }
    return;
  }

  // ---------------- encoder body: BM=64, K1=32 (14 used), type-sorted, + Y emit
  {
    constexpr int BM = 64, SKz = 40, HS = 144;
    bf16* Zt = smem;                 // 64*40
    bf16* Hid = smem + BM * SKz;     // 64*144
    int idx = blockIdx.x - eeBlocks;
    int t = idx / ngrid64;
    int bx = idx - t * ngrid64;
    int rs = ts[t], re = ts[t + 1];
    int row0 = rs + bx * BM;
    if (row0 >= re) return;
    for (int i = tid; i < BM; i += 512) gIdx[i] = (row0 + i < re) ? perm[row0 + i] : -1;
    __syncthreads();
    for (int i = tid; i < BM * 32; i += 512) {
      int row = i >> 5, k = i & 31;
      int g = gIdx[row];
      bf16 v = __float2bfloat16(0.f);
      if (g >= 0 && k < 14) v = (k < 6) ? x[(size_t)g * 6 + k] : pe[(size_t)g * 8 + (k - 6)];
      Zt[row * SKz + k] = v;
    }
    __syncthreads();
    const bf16* W1t = encW1 + (size_t)t * 4096;
    const bf16* W2t = encW2 + (size_t)t * 16384;
    floatx4 acc[2][2];
    #pragma unroll
    for (int rt = 0; rt < 2; rt++)
      #pragma unroll
      for (int c = 0; c < 2; c++) acc[rt][c] = (floatx4){0.f, 0.f, 0.f, 0.f};
    {
      short8 bfr0 = *(const short8*)(W1t + (((size_t)(wc * 2 + 0)) * 64 + lane) * 8);
      short8 bfr1 = *(const short8*)(W1t + (((size_t)(wc * 2 + 1)) * 64 + lane) * 8);
      #pragma unroll
      for (int rt = 0; rt < 2; rt++) {
        short8 a = *(const short8*)(&Zt[(wr * 32 + rt * 16 + colq) * SKz + quad * 8]);
        acc[rt][0] = __builtin_amdgcn_mfma_f32_16x16x32_bf16(a, bfr0, acc[rt][0], 0, 0, 0);
        acc[rt][1] = __builtin_amdgcn_mfma_f32_16x16x32_bf16(a, bfr1, acc[rt][1], 0, 0, 0);
      }
    }
    #pragma unroll
    for (int c = 0; c < 2; c++) {
      int col = wc * 32 + c * 16 + colq;
      float bv = b2f(encB1[t * HDIM + col]);
      #pragma unroll
      for (int rt = 0; rt < 2; rt++)
        #pragma unroll
        for (int r = 0; r < 4; r++)
          Hid[(wr * 32 + rt * 16 + quad * 4 + r) * HS + col] =
              __float2bfloat16(fmaxf(acc[rt][c][r] + bv, 0.f));
    }
    __syncthreads();
    floatx4 acc2[2][2];
    #pragma unroll
    for (int rt = 0; rt < 2; rt++)
      #pragma unroll
      for (int c = 0; c < 2; c++) acc2[rt][c] = (floatx4){0.f, 0.f, 0.f, 0.f};
    #pragma unroll
    for (int ks = 0; ks < 4; ks++) {
      short8 bfr0 = *(const short8*)(W2t + (((size_t)(wc * 2 + 0) * 4 + ks) * 64 + lane) * 8);
      short8 bfr1 = *(const short8*)(W2t + (((size_t)(wc * 2 + 1) * 4 + ks) * 64 + lane) * 8);
      #pragma unroll
      for (int rt = 0; rt < 2; rt++) {
        short8 a = *(const short8*)(&Hid[(wr * 32 + rt * 16 + colq) * HS + ks * 32 + quad * 8]);
        acc2[rt][0] = __builtin_amdgcn_mfma_f32_16x16x32_bf16(a, bfr0, acc2[rt][0], 0, 0, 0);
        acc2[rt][1] = __builtin_amdgcn_mfma_f32_16x16x32_bf16(a, bfr1, acc2[rt][1], 0, 0, 0);
      }
    }
    __syncthreads();   // all Hid reads done before overwrite with h
    #pragma unroll
    for (int c = 0; c < 2; c++) {
      int col = wc * 32 + c * 16 + colq;
      float bv = b2f(encB2[t * HDIM + col]);
      #pragma unroll
      for (int rt = 0; rt < 2; rt++)
        #pragma unroll
        for (int r = 0; r < 4; r++) {
          int row = wr * 32 + rt * 16 + quad * 4 + r;
          int g = gIdx[row];
          bf16 hb = __float2bfloat16(acc2[rt][c][r] + bv);
          Hid[row * HS + col] = hb;
          if (g >= 0) h_nodes[(size_t)g * HDIM + col] = hb;
        }
    }
    __syncthreads();

    // ---- layer-0 Y emit: Y = h @ yW1a / yW1b, scattered via gIdx
    #pragma unroll
    for (int which = 0; which < 2; which++) {
      const bf16* Wp = which ? yW1b : yW1a;
      bf16* outy = which ? ysB : ysA;
      floatx4 accy[2][2];
      #pragma unroll
      for (int rt = 0; rt < 2; rt++)
        #pragma unroll
        for (int c = 0; c < 2; c++) accy[rt][c] = (floatx4){0.f, 0.f, 0.f, 0.f};
      #pragma unroll
      for (int ks = 0; ks < 4; ks++) {
        short8 bfr0 = *(const short8*)(Wp + (((size_t)(wc * 2 + 0) * 4 + ks) * 64 + lane) * 8);
        short8 bfr1 = *(const short8*)(Wp + (((size_t)(wc * 2 + 1) * 4 + ks) * 64 + lane) * 8);
        #pragma unroll
        for (int rt = 0; rt < 2; rt++) {
          short8 a = *(const short8*)(&Hid[(wr * 32 + rt * 16 + colq) * HS + ks * 32 + quad * 8]);
          accy[rt][0] = __builtin_amdgcn_mfma_f32_16x16x32_bf16(a, bfr0, accy[rt][0], 0, 0, 0);
          accy[rt][1] = __builtin_amdgcn_mfma_f32_16x16x32_bf16(a, bfr1, accy[rt][1], 0, 0, 0);
        }
      }
      #pragma unroll
      for (int c = 0; c < 2; c++) {
        int col = wc * 32 + c * 16 + colq;
        #pragma unroll
        for (int rt = 0; rt < 2; rt++)
          #pragma unroll
          for (int r = 0; r < 4; r++) {
            int g = gIdx[wr * 32 + rt * 16 + quad * 4 + r];
            if (g >= 0) outy[(size_t)g * HDIM + col] = __float2bfloat16(accy[rt][c][r]);
          }
      }
    }
  }
}

// -------------------------------------------------- typed decoder (type-sorted MFMA)
__global__ void __launch_bounds__(256) dec_kernel(
    const bf16* __restrict__ in0,
    const int* __restrict__ perm, const int* __restrict__ ts, const int* __restrict__ flagp,
    const bf16* __restrict__ W1p, const bf16* __restrict__ b1v,
    const bf16* __restrict__ W2p, const bf16* __restrict__ b2v,
    void* __restrict__ outp) {
  constexpr int BM = 64, RT = 4, SK = 144, HS = 144;
  int t = blockIdx.y;
  int rs = ts[t], re = ts[t + 1];
  int row0 = rs + blockIdx.x * BM;
  if (row0 >= re) return;
  __shared__ bf16 Zt[BM * SK];
  __shared__ bf16 Hid[BM * HS];
  __shared__ int gIdx[BM];
  const int tid = threadIdx.x;
  const int lane = tid & 63, wave = tid >> 6, colq = lane & 15, quad = lane >> 4;
  for (int i = tid; i < BM; i += 256) gIdx[i] = (row0 + i < re) ? perm[row0 + i] : -1;
  __syncthreads();
  {
    int row = tid >> 2, sub = tid & 3;
    int g = gIdx[row];
    #pragma unroll
    for (int j = 0; j < 4; j++) {
      int seg = j * 4 + sub;
      uint4 v = {0u, 0u, 0u, 0u};
      if (g >= 0) v = *(const uint4*)(in0 + (size_t)g * HDIM + seg * 8);
      *(uint4*)(&Zt[row * SK + seg * 8]) = v;
    }
  }
  __syncthreads();
  const bf16* W1t = W1p + (size_t)t * 16384;
  const bf16* W2t = W2p + (size_t)t * 16384;
  floatx4 acc[RT][2];
  #pragma unroll
  for (int rt = 0; rt < RT; rt++)
    #pragma unroll
    for (int c = 0; c < 2; c++) acc[rt][c] = (floatx4){0.f, 0.f, 0.f, 0.f};
  #pragma unroll
  for (int ks = 0; ks < 4; ks++) {
    short8 bfr0 = *(const short8*)(W1t + (((size_t)(wave * 2 + 0) * 4 + ks) * 64 + lane) * 8);
    short8 bfr1 = *(const short8*)(W1t + (((size_t)(wave * 2 + 1) * 4 + ks) * 64 + lane) * 8);
    #pragma unroll
    for (int rt = 0; rt < RT; rt++) {
      short8 a = *(const short8*)(&Zt[(rt * 16 + colq) * SK + ks * 32 + quad * 8]);
      acc[rt][0] = __builtin_amdgcn_mfma_f32_16x16x32_bf16(a, bfr0, acc[rt][0], 0, 0, 0);
      acc[rt][1] = __builtin_amdgcn_mfma_f32_16x16x32_bf16(a, bfr1, acc[rt][1], 0, 0, 0);
    }
  }
  #pragma unroll
  for (int c = 0; c < 2; c++) {
    int col = wave * 32 + c * 16 + colq;
    float bv = b2f(b1v[t * HDIM + col]);
    #pragma unroll
    for (int rt = 0; rt < RT; rt++)
      #pragma unroll
      for (int r = 0; r < 4; r++)
        Hid[(rt * 16 + quad * 4 + r) * HS + col] =
            __float2bfloat16(fmaxf(acc[rt][c][r] + bv, 0.f));
  }
  __syncthreads();
  floatx4 acc2[RT];
  #pragma unroll
  for (int rt = 0; rt < RT; rt++) acc2[rt] = (floatx4){0.f, 0.f, 0.f, 0.f};
  #pragma unroll
  for (int ks = 0; ks < 4; ks++) {
    short8 bfr0 = *(const short8*)(W2t + (((size_t)0 * 4 + ks) * 64 + lane) * 8);
    #pragma unroll
    for (int rt = 0; rt < RT; rt++) {
      short8 a = *(const short8*)(&Hid[(rt * 16 + colq) * HS + ks * 32 + quad * 8]);
      acc2[rt] = __builtin_amdgcn_mfma_f32_16x16x32_bf16(a, bfr0, acc2[rt], 0, 0, 0);
    }
  }
  if (wave == 0 && colq < 4) {
    int isBf = flagp[0];
    float bv = b2f(b2v[t * 4 + colq]);
    #pragma unroll
    for (int rt = 0; rt < RT; rt++)
      #pragma unroll
      for (int r = 0; r < 4; r++) {
        int g = gIdx[rt * 16 + quad * 4 + r];
        if (g >= 0) {
          float v = acc2[rt][r] + bv;
          if (isBf) ((bf16*)outp)[(size_t)g * 4 + colq] = __float2bfloat16(v);
          else      ((float*)outp)[(size_t)g * 4 + colq] = v;
        }
      }
  }
}

// ---------------------------------------------------------------- launcher
extern "C" void kernel_launch(void* const* d_in, const int* in_sizes, int n_in,
                              void* d_out, int out_size, void* d_ws, size_t ws_size,
                              hipStream_t stream) {
  const int* edge_index = (const int*)d_in[27];
  const int* node_types = (const int*)d_in[28];
  const int N = in_sizes[28];
  const int E = in_sizes[2] / 4;
  const int L = in_sizes[12] / HDIM;
  const int* srcI = edge_index;
  const int* dstI = edge_index + E;

  CanonDesc cd;
  int total = 0;
  for (int i = 0; i < NCANON; i++) { cd.src[i] = d_in[i]; cd.prefix[i] = total; total += in_sizes[i]; }
  cd.prefix[NCANON] = total;

  char* wsb = (char*)d_ws;
  size_t off = 0;
  auto alloc = [&](size_t bytes) -> void* {
    void* p = wsb + off;
    off += (bytes + 255) & ~(size_t)255;
    return p;
  };
  int*  flag      = (int*)alloc(256);
  bf16* arena     = (bf16*)alloc((size_t)total * 2);
  bf16* h_nodes   = (bf16*)alloc((size_t)N * HDIM * 2);
  bf16* h_edges   = (bf16*)alloc((size_t)E * HDIM * 2);
  bf16* ysrcb     = (bf16*)alloc((size_t)N * HDIM * 2);
  bf16* ydstb     = (bf16*)alloc((size_t)N * HDIM * 2);
  bf16* eaS       = (bf16*)alloc((size_t)E * 4 * 2);
  // m_node placed adjacent to counts/cursor so canon's tail blocks zero all three
  float* m_node   = (float*)alloc((size_t)N * HDIM * 4);
  int* counts     = (int*)alloc((size_t)N * 4);
  int* cursor     = (int*)alloc((size_t)N * 4);
  int* row_start  = (int*)alloc((size_t)(N + 1) * 4);
  int* bsum       = (int*)alloc(260 * 4);
  int* srcS       = (int*)alloc((size_t)E * 4);
  int* dstS       = (int*)alloc((size_t)E * 4);
  int* tsArr      = (int*)alloc(64);
  int* permT      = (int*)alloc((size_t)N * 4);
  bf16* eeW1p  = (bf16*)alloc(4096 * 2);
  bf16* eeW2p  = (bf16*)alloc(16384 * 2);
  bf16* encW1p = (bf16*)alloc(3 * 4096 * 2);
  bf16* encW2p = (bf16*)alloc(3 * 16384 * 2);
  bf16* decW1p = (bf16*)alloc(3 * 16384 * 2);
  bf16* decW2p = (bf16*)alloc(3 * 16384 * 2);
  bf16* euW1a  = (bf16*)alloc((size_t)L * 16384 * 2);
  bf16* euW1b  = (bf16*)alloc((size_t)L * 16384 * 2);
  bf16* euW1c  = (bf16*)alloc((size_t)L * 16384 * 2);
  bf16* euW2p  = (bf16*)alloc((size_t)L * 16384 * 2);
  bf16* nuW1p  = (bf16*)alloc((size_t)L * 32768 * 2);
  bf16* nuW2p  = (bf16*)alloc((size_t)L * 16384 * 2);
  bf16* fuW1p  = (bf16*)alloc((size_t)L * 16384 * 2);
  bf16* fuW2p  = (bf16*)alloc((size_t)L * 16384 * 2);

  const bf16* cX     = arena + cd.prefix[0];
  const bf16* cPE    = arena + cd.prefix[1];
  const bf16* cEA    = arena + cd.prefix[2];
  const bf16* cEncW1 = arena + cd.prefix[3];
  const bf16* cEncB1 = arena + cd.prefix[4];
  const bf16* cEncW2 = arena + cd.prefix[5];
  const bf16* cEncB2 = arena + cd.prefix[6];
  const bf16* cEeW1  = arena + cd.prefix[7];
  const bf16* cEeB1  = arena + cd.prefix[8];
  const bf16* cEeW2  = arena + cd.prefix[9];
  const bf16* cEeB2  = arena + cd.prefix[10];
  const bf16* cEuW1  = arena + cd.prefix[11];
  const bf16* cEuB1  = arena + cd.prefix[12];
  const bf16* cEuW2  = arena + cd.prefix[13];
  const bf16* cEuB2  = arena + cd.prefix[14];
  const bf16* cNuW1  = arena + cd.prefix[15];
  const bf16* cNuB1  = arena + cd.prefix[16];
  const bf16* cNuW2  = arena + cd.prefix[17];
  const bf16* cNuB2  = arena + cd.prefix[18];
  const bf16* cFuW1  = arena + cd.prefix[19];
  const bf16* cFuB1  = arena + cd.prefix[20];
  const bf16* cFuW2  = arena + cd.prefix[21];
  const bf16* cFuB2  = arena + cd.prefix[22];
  const bf16* cDecW1 = arena + cd.prefix[23];
  const bf16* cDecB1 = arena + cd.prefix[24];
  const bf16* cDecW2 = arena + cd.prefix[25];
  const bf16* cDecB2 = arena + cd.prefix[26];

  // canon (+ zero m_node/counts/cursor, contiguous 256-aligned region)
  int canonBlocks = (total + 255) / 256;
  size_t zbytes = (size_t)((char*)cursor - (char*)m_node) + (size_t)N * 4;
  int zquads = (int)(zbytes / 16);
  int zBlocks = (zquads + 255) / 256;
  canon_kernel<<<canonBlocks + zBlocks, 256, 0, stream>>>(
      cd, (const unsigned short*)d_in[0], flag, arena, total, canonBlocks,
      (uint4*)m_node, zquads);

  // hist + tsort (one dispatch, 1024 threads)
  int hb = (E + 1023) / 1024;
  hist_tsort_kernel<<<hb + 1, 1024, 0, stream>>>(dstI, counts, E, hb,
                                                 node_types, tsArr, permT, N);

  PackJobs PJ;
  int nj = 0;
  PJ.j[nj++] = {cEeW1, eeW1p, 4, 1, 128};
  PJ.j[nj++] = {cEeW2, eeW2p, 128, 4, 128};
  for (int l = 0; l < L; l++) {
    const bf16* w1 = cEuW1 + (size_t)l * 384 * HDIM;
    PJ.j[nj++] = {w1,                 euW1a + (size_t)l * 16384, 128, 4, 128};
    PJ.j[nj++] = {w1 + 128 * HDIM,    euW1b + (size_t)l * 16384, 128, 4, 128};
    PJ.j[nj++] = {w1 + 256 * HDIM,    euW1c + (size_t)l * 16384, 128, 4, 128};
    PJ.j[nj++] = {cEuW2 + (size_t)l * HDIM * HDIM, euW2p + (size_t)l * 16384, 128, 4, 128};
    PJ.j[nj++] = {cNuW1 + (size_t)l * 256 * HDIM,  nuW1p + (size_t)l * 32768, 256, 8, 128};
    PJ.j[nj++] = {cNuW2 + (size_t)l * HDIM * HDIM, nuW2p + (size_t)l * 16384, 128, 4, 128};
    PJ.j[nj++] = {cFuW1 + (size_t)l * HDIM * HDIM, fuW1p + (size_t)l * 16384, 128, 4, 128};
    PJ.j[nj++] = {cFuW2 + (size_t)l * HDIM * HDIM, fuW2p + (size_t)l * 16384, 128, 4, 128};
  }
  for (int t = 0; t < 3; t++) {
    PJ.j[nj++] = {cEncW1 + (size_t)t * 14 * HDIM,   encW1p + (size_t)t * 4096, 14, 1, 128};
    PJ.j[nj++] = {cEncW2 + (size_t)t * HDIM * HDIM, encW2p + (size_t)t * 16384, 128, 4, 128};
    PJ.j[nj++] = {cDecW1 + (size_t)t * HDIM * HDIM, decW1p + (size_t)t * 16384, 128, 4, 128};
    PJ.j[nj++] = {cDecW2 + (size_t)t * HDIM * 4,    decW2p + (size_t)t * 16384, 128, 4, 4};
  }
  pack_all_kernel<<<dim3(16, nj), 256, 0, stream>>>(PJ);

  int nb = (N + 255) / 256;
  scan1_kernel<<<nb, 256, 0, stream>>>(counts, bsum, N);
  scan2_kernel<<<1, 64, 0, stream>>>(bsum, nb);
  scan3_kernel<<<nb, 256, 0, stream>>>(counts, bsum, row_start, N, nb);
  scatter_kernel<<<(E + 255) / 256, 256, 0, stream>>>(srcI, dstI, row_start, cursor,
                                                      cEA, eaS, srcS, dstS, E);

  int ngrid64  = (N + 63) / 64;
  int egrid64  = (E + 63) / 64;
  int egrid128 = (E + 127) / 128;

  // fused encoder + edge-encoder + layer-0 Y emit (replaces ygemm)
  encee_kernel<<<egrid128 + 3 * ngrid64, 512, 0, stream>>>(
      egrid128, ngrid64,
      eaS, eeW1p, cEeB1, eeW2p, cEeB2, h_edges, E,
      cX, cPE, permT, tsArr, encW1p, cEncB1, encW2p, cEncB2, h_nodes,
      euW1a, euW1b, ysrcb, ydstb);

  for (int l = 0; l < L; l++) {
    if (l + 1 < L) {
      eu_kernel<true><<<egrid64, 512, 0, stream>>>(
          h_edges, ysrcb, ydstb, srcS, dstS,
          euW1c + (size_t)l * 16384, cEuB1 + l * HDIM,
          euW2p + (size_t)l * 16384, cEuB2 + l * HDIM, h_edges, m_node, E);
    } else {
      eu_kernel<false><<<egrid64, 512, 0, stream>>>(
          h_edges, ysrcb, ydstb, srcS, dstS,
          euW1c + (size_t)l * 16384, cEuB1 + l * HDIM,
          euW2p + (size_t)l * 16384, cEuB2 + l * HDIM, h_edges, m_node, E);
    }
    bool hasNext = (l + 1 < L);
    node_kernel<<<ngrid64, 512, 0, stream>>>(
        h_nodes, m_node,
        nuW1p + (size_t)l * 32768, cNuB1 + l * HDIM,
        nuW2p + (size_t)l * 16384, cNuB2 + l * HDIM,
        fuW1p + (size_t)l * 16384, cFuB1 + l * HDIM,
        fuW2p + (size_t)l * 16384, cFuB2 + l * HDIM,
        hasNext ? euW1a + (size_t)(l + 1) * 16384 : nullptr,
        hasNext ? euW1b + (size_t)(l + 1) * 16384 : nullptr,
        ysrcb, ydstb, h_nodes, N);
  }

  dec_kernel<<<dim3(ngrid64, 3), 256, 0, stream>>>(
      h_nodes, permT, tsArr, flag, decW1p, cDecB1, decW2p, cDecB2, d_out);
  (void)n_in; (void)ws_size;
}

// Round 7
// 439.007 us; speedup vs baseline: 1.0298x; 1.0298x over previous
//
#include <hip/hip_runtime.h>
#include <hip/hip_bf16.h>

typedef __hip_bfloat16 bf16;
typedef __attribute__((ext_vector_type(8))) short short8;   // 8 bf16 frag
typedef __attribute__((ext_vector_type(4))) float floatx4;  // MFMA C/D frag

#define HDIM 128
#define NCANON 27

__device__ __forceinline__ float b2f(bf16 v) { return __bfloat162float(v); }
__device__ __forceinline__ float s2f(short s) {
  return __uint_as_float(((unsigned int)(unsigned short)s) << 16);
}
__device__ __forceinline__ short f2s(float f) {
  return (short)__bfloat16_as_ushort(__float2bfloat16(f));
}

struct CanonDesc {
  const void* src[NCANON];
  int prefix[NCANON + 1];
};

// ---- canon + inlined dtype detect + zero-fill of m_node/counts/cursor (tail blocks)
__global__ void canon_kernel(CanonDesc d, const unsigned short* __restrict__ xraw,
                             int* __restrict__ flagOut, bf16* __restrict__ out, int total,
                             int canonBlocks, uint4* __restrict__ zbase, int zquads) {
  int tid = threadIdx.x;
  if (blockIdx.x >= canonBlocks) {
    int i = (blockIdx.x - canonBlocks) * 256 + tid;
    if (i < zquads) { uint4 z = {0u, 0u, 0u, 0u}; zbase[i] = z; }
    return;
  }
  __shared__ int sflag;
  if (tid < 64) {
    unsigned short u = xraw[2 * tid];
    int e = (u >> 7) & 0xFF;
    int ok = (u == 0) || (e >= 100 && e <= 140);
    unsigned long long m = __ballot(ok);
    if (tid == 0) sflag = (__popcll(m) >= 48) ? 1 : 0;
  }
  __syncthreads();
  int isBf = sflag;
  if (blockIdx.x == 0 && tid == 0) flagOut[0] = isBf;
  int t = blockIdx.x * 256 + tid;
  if (t >= total) return;
  int lo = 0, hi = NCANON;
  while (lo + 1 < hi) { int mid = (lo + hi) >> 1; if (d.prefix[mid] <= t) lo = mid; else hi = mid; }
  int off = t - d.prefix[lo];
  out[t] = isBf ? ((const bf16*)d.src[lo])[off]
                : __float2bfloat16(((const float*)d.src[lo])[off]);
}

// ---------------- hist (dst histogram) + tsort (type counting sort), one dispatch
__global__ void __launch_bounds__(1024) hist_tsort_kernel(
    const int* __restrict__ dst, int* __restrict__ cnt, int E, int hb,
    const int* __restrict__ types, int* __restrict__ ts, int* __restrict__ perm, int n) {
  if (blockIdx.x < hb) {
    int e = blockIdx.x * 1024 + threadIdx.x;
    if (e < E) atomicAdd(&cnt[dst[e]], 1);
    return;
  }
  // ---- tsort body (single block, 1024 threads)
  __shared__ int wc[16][3];
  __shared__ int base[3];
  int tid = threadIdx.x, lane = tid & 63, wave = tid >> 6;
  int c0 = 0, c1 = 0, c2 = 0;
  for (int i = tid; i < n; i += 1024) {
    int t = types[i];
    c0 += (t == 0); c1 += (t == 1); c2 += (t == 2);
  }
  #pragma unroll
  for (int d = 32; d; d >>= 1) {
    c0 += __shfl_down(c0, d); c1 += __shfl_down(c1, d); c2 += __shfl_down(c2, d);
  }
  if (lane == 0) { wc[wave][0] = c0; wc[wave][1] = c1; wc[wave][2] = c2; }
  __syncthreads();
  if (tid == 0) {
    int t0 = 0, t1 = 0;
    for (int w = 0; w < 16; w++) { t0 += wc[w][0]; t1 += wc[w][1]; }
    ts[0] = 0; ts[1] = t0; ts[2] = t0 + t1; ts[3] = n;
    base[0] = 0; base[1] = t0; base[2] = t0 + t1;
  }
  __syncthreads();
  for (int i0 = 0; i0 < n; i0 += 1024) {
    int i = i0 + tid;
    int t = (i < n) ? types[i] : -1;
    unsigned long long m0 = __ballot(t == 0);
    unsigned long long m1 = __ballot(t == 1);
    unsigned long long m2 = __ballot(t == 2);
    if (lane == 0) { wc[wave][0] = __popcll(m0); wc[wave][1] = __popcll(m1); wc[wave][2] = __popcll(m2); }
    __syncthreads();
    if (i < n) {
      unsigned long long mt = (t == 0) ? m0 : ((t == 1) ? m1 : m2);
      unsigned long long below = (lane == 0) ? 0ull : ((1ull << lane) - 1ull);
      int r = __popcll(mt & below);
      int woff = 0;
      for (int w = 0; w < wave; w++) woff += wc[w][t];
      perm[base[t] + woff + r] = i;
    }
    __syncthreads();
    if (tid == 0) {
      int a0 = 0, a1 = 0, a2 = 0;
      for (int w = 0; w < 16; w++) { a0 += wc[w][0]; a1 += wc[w][1]; a2 += wc[w][2]; }
      base[0] += a0; base[1] += a1; base[2] += a2;
    }
    __syncthreads();
  }
}

__global__ void scan1_kernel(const int* __restrict__ cnt, int* __restrict__ bsum, int n) {
  int tid = threadIdx.x, lane = tid & 63, wave = tid >> 6;
  int i = blockIdx.x * 256 + tid;
  int v = (i < n) ? cnt[i] : 0;
  #pragma unroll
  for (int d = 32; d; d >>= 1) v += __shfl_down(v, d);
  __shared__ int ws[4];
  if (lane == 0) ws[wave] = v;
  __syncthreads();
  if (tid == 0) bsum[blockIdx.x] = ws[0] + ws[1] + ws[2] + ws[3];
}

__global__ void scan2_kernel(int* __restrict__ bsum, int nb) {   // nb <= 128; 64 threads
  int lane = threadIdx.x;
  int a0 = (lane < nb) ? bsum[lane] : 0;
  int b0 = (64 + lane < nb) ? bsum[64 + lane] : 0;
  int a = a0, b = b0;
  #pragma unroll
  for (int d = 1; d < 64; d <<= 1) { int t = __shfl_up(a, d); if (lane >= d) a += t; }
  int totA = __shfl(a, 63);
  #pragma unroll
  for (int d = 1; d < 64; d <<= 1) { int t = __shfl_up(b, d); if (lane >= d) b += t; }
  int totB = __shfl(b, 63);
  if (lane < nb) bsum[lane] = a - a0;
  if (64 + lane < nb) bsum[64 + lane] = b - b0 + totA;
  if (lane == 0) bsum[nb] = totA + totB;
}

__global__ void scan3_kernel(const int* __restrict__ cnt, const int* __restrict__ bsum,
                             int* __restrict__ row_start, int n, int nb) {
  __shared__ int sh[256];
  int tid = threadIdx.x;
  int i = blockIdx.x * 256 + tid;
  int v = (i < n) ? cnt[i] : 0;
  sh[tid] = v;
  __syncthreads();
  #pragma unroll
  for (int off = 1; off < 256; off <<= 1) {
    int t = (tid >= off) ? sh[tid - off] : 0;
    __syncthreads();
    sh[tid] += t;
    __syncthreads();
  }
  if (i < n) row_start[i] = bsum[blockIdx.x] + sh[tid] - v;
  if (blockIdx.x == 0 && tid == 0) row_start[n] = bsum[nb];
}

// scatter: permutes edge_attr into dst-sorted order too
__global__ void scatter_kernel(const int* __restrict__ src, const int* __restrict__ dst,
                               const int* __restrict__ row_start, int* __restrict__ cursor,
                               const bf16* __restrict__ ea, bf16* __restrict__ eaS,
                               int* __restrict__ srcS, int* __restrict__ dstS, int E) {
  int e = blockIdx.x * 256 + threadIdx.x;
  if (e < E) {
    int d = dst[e];
    int pos = row_start[d] + atomicAdd(&cursor[d], 1);
    srcS[pos] = src[e];
    dstS[pos] = d;
    *(uint2*)(eaS + (size_t)pos * 4) = *(const uint2*)(ea + (size_t)e * 4);
  }
}

// -------------------------------------------------- fused weight pre-pack (B-frag order)
struct PackJob { const bf16* src; bf16* dst; int Ksrc; int KS; int srcCols; };
struct PackJobs { PackJob j[40]; };

__global__ void pack_all_kernel(PackJobs J) {
  PackJob job = J.j[blockIdx.y];
  int idx = blockIdx.x * 256 + threadIdx.x;
  int total = 8 * job.KS * 64;
  if (idx >= total) return;
  int lane = idx & 63;
  int ks = (idx >> 6) % job.KS;
  int ct = idx / (64 * job.KS);
  bf16* o = job.dst + (size_t)idx * 8;
  int ncol = ct * 16 + (lane & 15);
  int kb = ks * 32 + ((lane >> 4) & 3) * 8;
  #pragma unroll
  for (int jj = 0; jj < 8; jj++) {
    int k = kb + jj;
    o[jj] = (k < job.Ksrc && ncol < job.srcCols)
              ? job.src[(size_t)k * job.srcCols + ncol] : __float2bfloat16(0.f);
  }
}

// ----------------------- edge-update + fused dst-segment aggregation (layers >= 1)
// Round-3 best config: BM=64, 512 threads, 8 waves x 1 col-tile, scalar scan.
template<bool WRITE_HE>
__global__ void __launch_bounds__(512) eu_kernel(
    const bf16* __restrict__ he, const bf16* __restrict__ ysrc, const bf16* __restrict__ ydst,
    const int* __restrict__ srcS, const int* __restrict__ dstS,
    const bf16* __restrict__ W1p, const bf16* __restrict__ b1v,
    const bf16* __restrict__ W2p, const bf16* __restrict__ b2v,
    bf16* __restrict__ outp, float* __restrict__ mnode, int M) {
  constexpr int BM = 64, RT = 4, SK = 272;
  __shared__ bf16 Zt[BM * SK];
  __shared__ int dstLds[BM];
  const int tid = threadIdx.x;
  const int lane = tid & 63, wave = tid >> 6, colq = lane & 15, quad = lane >> 4;
  // XCD-aware bijective swizzle (dst-sorted edges -> L2 locality per XCD)
  const int nwg = gridDim.x, bid = blockIdx.x;
  const int qq = nwg >> 3, rr = nwg & 7;
  const int xcd = bid & 7, bidx = bid >> 3;
  const int blk = (xcd < rr ? xcd * (qq + 1) : rr * (qq + 1) + (xcd - rr) * qq) + bidx;
  const int row0 = blk * BM;
  {
    int row = tid >> 3, sub = tid & 7;
    int gr = row0 + row;
    bool ok = gr < M;
    int g0 = ok ? srcS[gr] : 0;
    int g1 = ok ? dstS[gr] : 0;
    if (sub == 0) dstLds[row] = ok ? g1 : -1;
    #pragma unroll
    for (int j = 0; j < 4; j++) {
      int c = j * 8 + sub;
      int part = c >> 4, seg = c & 15;
      if (part == 0) {
        short8 o = {0, 0, 0, 0, 0, 0, 0, 0};
        if (ok) {
          short8 a = *(const short8*)(ysrc + (size_t)g0 * HDIM + seg * 8);
          short8 b = *(const short8*)(ydst + (size_t)g1 * HDIM + seg * 8);
          #pragma unroll
          for (int k = 0; k < 8; k++) o[k] = f2s(s2f(a[k]) + s2f(b[k]));
        }
        *(short8*)(&Zt[row * SK + seg * 8]) = o;
      } else {
        uint4 v = {0u, 0u, 0u, 0u};
        if (ok) v = *(const uint4*)(he + (size_t)gr * HDIM + seg * 8);
        *(uint4*)(&Zt[row * SK + 128 + seg * 8]) = v;
      }
    }
  }
  __syncthreads();

  floatx4 acc[RT];
  #pragma unroll
  for (int rt = 0; rt < RT; rt++) acc[rt] = (floatx4){0.f, 0.f, 0.f, 0.f};
  #pragma unroll
  for (int ks = 0; ks < 4; ks++) {
    short8 bfr = *(const short8*)(W1p + (((size_t)wave * 4 + ks) * 64 + lane) * 8);
    #pragma unroll
    for (int rt = 0; rt < RT; rt++) {
      short8 a = *(const short8*)(&Zt[(rt * 16 + colq) * SK + 128 + ks * 32 + quad * 8]);
      acc[rt] = __builtin_amdgcn_mfma_f32_16x16x32_bf16(a, bfr, acc[rt], 0, 0, 0);
    }
  }
  {
    int col = wave * 16 + colq;
    float bv = b2f(b1v[col]);
    #pragma unroll
    for (int rt = 0; rt < RT; rt++)
      #pragma unroll
      for (int r = 0; r < 4; r++) {
        int lrow = rt * 16 + quad * 4 + r;
        float v = acc[rt][r] + bv + b2f(Zt[lrow * SK + col]);
        Zt[lrow * SK + col] = __float2bfloat16(fmaxf(v, 0.f));
      }
  }
  __syncthreads();

  #pragma unroll
  for (int rt = 0; rt < RT; rt++) acc[rt] = (floatx4){0.f, 0.f, 0.f, 0.f};
  #pragma unroll
  for (int ks = 0; ks < 4; ks++) {
    short8 bfr = *(const short8*)(W2p + (((size_t)wave * 4 + ks) * 64 + lane) * 8);
    #pragma unroll
    for (int rt = 0; rt < RT; rt++) {
      short8 a = *(const short8*)(&Zt[(rt * 16 + colq) * SK + ks * 32 + quad * 8]);
      acc[rt] = __builtin_amdgcn_mfma_f32_16x16x32_bf16(a, bfr, acc[rt], 0, 0, 0);
    }
  }
  {
    int col = wave * 16 + colq;
    float bv = b2f(b2v[col]);
    #pragma unroll
    for (int rt = 0; rt < RT; rt++)
      #pragma unroll
      for (int r = 0; r < 4; r++) {
        int lrow = rt * 16 + quad * 4 + r;
        float v = acc[rt][r] + bv + b2f(Zt[lrow * SK + 128 + col]);
        Zt[lrow * SK + 128 + col] = __float2bfloat16(v);
      }
  }
  __syncthreads();

  if (WRITE_HE) {
    #pragma unroll
    for (int i = tid; i < BM * 16; i += 512) {
      int row = i >> 4, seg = i & 15;
      int gr = row0 + row;
      if (gr < M)
        *(uint4*)(outp + (size_t)gr * HDIM + seg * 8) = *(const uint4*)(&Zt[row * SK + 128 + seg * 8]);
    }
  }
  {
    int col = tid & 127;
    int q4 = tid >> 7;                  // 0..3: quarter of 16 rows
    int rbeg = q4 * 16, rend = rbeg + 16;
    float s = 0.f;
    int runDst = dstLds[rbeg];
    bool touchStart = true;
    for (int r = rbeg; r < rend; r++) {
      int d = dstLds[r];
      if (d != runDst) {
        if (runDst >= 0) {
          float* mp = &mnode[(size_t)runDst * HDIM + col];
          if (touchStart) atomicAdd(mp, s); else *mp = s;
        }
        runDst = d; s = 0.f; touchStart = false;
      }
      s += b2f(Zt[r * SK + 128 + col]);
    }
    if (runDst >= 0) atomicAdd(&mnode[(size_t)runDst * HDIM + col], s);
  }
}

// ----------------------- FUSED edge-encoder + layer-0 edge-update + aggregation
// Deletes the 82 MB h_edges write (ee) + 82 MB read (eu0). LDS live-range plan in
// SK=272: [0..127] ysum -> eu-hidden; [128..255] ea -> ee-hid1 -> h_e -> m_edge.
__global__ void __launch_bounds__(512) eeeu_kernel(
    const bf16* __restrict__ eaS,
    const bf16* __restrict__ eeW1, const bf16* __restrict__ eeB1,
    const bf16* __restrict__ eeW2, const bf16* __restrict__ eeB2,
    const bf16* __restrict__ ysrc, const bf16* __restrict__ ydst,
    const int* __restrict__ srcS, const int* __restrict__ dstS,
    const bf16* __restrict__ W1p, const bf16* __restrict__ b1v,
    const bf16* __restrict__ W2p, const bf16* __restrict__ b2v,
    bf16* __restrict__ outp, float* __restrict__ mnode, int M) {
  constexpr int BM = 64, RT = 4, SK = 272;
  __shared__ bf16 Zt[BM * SK];
  __shared__ int dstLds[BM];
  const int tid = threadIdx.x;
  const int lane = tid & 63, wave = tid >> 6, colq = lane & 15, quad = lane >> 4;
  const int nwg = gridDim.x, bid = blockIdx.x;
  const int qq = nwg >> 3, rr = nwg & 7;
  const int xcd = bid & 7, bidx = bid >> 3;
  const int blk = (xcd < rr ? xcd * (qq + 1) : rr * (qq + 1) + (xcd - rr) * qq) + bidx;
  const int row0 = blk * BM;
  {
    int row = tid >> 3, sub = tid & 7;
    int gr = row0 + row;
    bool ok = gr < M;
    int g0 = ok ? srcS[gr] : 0;
    int g1 = ok ? dstS[gr] : 0;
    if (sub == 0) dstLds[row] = ok ? g1 : -1;
    #pragma unroll
    for (int j = 0; j < 2; j++) {
      int seg = j * 8 + sub;
      short8 o = {0, 0, 0, 0, 0, 0, 0, 0};
      if (ok) {
        short8 a = *(const short8*)(ysrc + (size_t)g0 * HDIM + seg * 8);
        short8 b = *(const short8*)(ydst + (size_t)g1 * HDIM + seg * 8);
        #pragma unroll
        for (int k = 0; k < 8; k++) o[k] = f2s(s2f(a[k]) + s2f(b[k]));
      }
      *(short8*)(&Zt[row * SK + seg * 8]) = o;
    }
    if (sub < 4) {   // ea region [128..159], zero-padded to K=32
      uint4 v = {0u, 0u, 0u, 0u};
      if (sub == 0 && ok) {
        uint2 e2 = *(const uint2*)(eaS + (size_t)gr * 4);
        v.x = e2.x; v.y = e2.y;
      }
      *(uint4*)(&Zt[row * SK + 128 + sub * 8]) = v;
    }
  }
  __syncthreads();

  floatx4 acc[RT];
  // ---- ee GEMM1: hid1 = relu(ea @ eeW1 + b1), K=32 (4 used)
  #pragma unroll
  for (int rt = 0; rt < RT; rt++) acc[rt] = (floatx4){0.f, 0.f, 0.f, 0.f};
  {
    short8 bfr = *(const short8*)(eeW1 + ((size_t)wave * 64 + lane) * 8);
    #pragma unroll
    for (int rt = 0; rt < RT; rt++) {
      short8 a = *(const short8*)(&Zt[(rt * 16 + colq) * SK + 128 + quad * 8]);
      acc[rt] = __builtin_amdgcn_mfma_f32_16x16x32_bf16(a, bfr, acc[rt], 0, 0, 0);
    }
  }
  __syncthreads();   // all ea reads done before overwriting [128..255]
  {
    int col = wave * 16 + colq;
    float bv = b2f(eeB1[col]);
    #pragma unroll
    for (int rt = 0; rt < RT; rt++)
      #pragma unroll
      for (int r = 0; r < 4; r++)
        Zt[(rt * 16 + quad * 4 + r) * SK + 128 + col] =
            __float2bfloat16(fmaxf(acc[rt][r] + bv, 0.f));
  }
  __syncthreads();

  // ---- ee GEMM2: h_e = hid1 @ eeW2 + b2  (reads [128..255], writes same region)
  #pragma unroll
  for (int rt = 0; rt < RT; rt++) acc[rt] = (floatx4){0.f, 0.f, 0.f, 0.f};
  #pragma unroll
  for (int ks = 0; ks < 4; ks++) {
    short8 bfr = *(const short8*)(eeW2 + (((size_t)wave * 4 + ks) * 64 + lane) * 8);
    #pragma unroll
    for (int rt = 0; rt < RT; rt++) {
      short8 a = *(const short8*)(&Zt[(rt * 16 + colq) * SK + 128 + ks * 32 + quad * 8]);
      acc[rt] = __builtin_amdgcn_mfma_f32_16x16x32_bf16(a, bfr, acc[rt], 0, 0, 0);
    }
  }
  __syncthreads();   // all hid1 reads done before overwrite
  {
    int col = wave * 16 + colq;
    float bv = b2f(eeB2[col]);
    #pragma unroll
    for (int rt = 0; rt < RT; rt++)
      #pragma unroll
      for (int r = 0; r < 4; r++)
        Zt[(rt * 16 + quad * 4 + r) * SK + 128 + col] =
            __float2bfloat16(acc[rt][r] + bv);
  }
  __syncthreads();

  // ---- eu GEMM1: hidden = relu(h_e @ W1c + b1 + ysum)   (epi rw [0..127])
  #pragma unroll
  for (int rt = 0; rt < RT; rt++) acc[rt] = (floatx4){0.f, 0.f, 0.f, 0.f};
  #pragma unroll
  for (int ks = 0; ks < 4; ks++) {
    short8 bfr = *(const short8*)(W1p + (((size_t)wave * 4 + ks) * 64 + lane) * 8);
    #pragma unroll
    for (int rt = 0; rt < RT; rt++) {
      short8 a = *(const short8*)(&Zt[(rt * 16 + colq) * SK + 128 + ks * 32 + quad * 8]);
      acc[rt] = __builtin_amdgcn_mfma_f32_16x16x32_bf16(a, bfr, acc[rt], 0, 0, 0);
    }
  }
  {
    int col = wave * 16 + colq;
    float bv = b2f(b1v[col]);
    #pragma unroll
    for (int rt = 0; rt < RT; rt++)
      #pragma unroll
      for (int r = 0; r < 4; r++) {
        int lrow = rt * 16 + quad * 4 + r;
        float v = acc[rt][r] + bv + b2f(Zt[lrow * SK + col]);
        Zt[lrow * SK + col] = __float2bfloat16(fmaxf(v, 0.f));
      }
  }
  __syncthreads();

  // ---- eu GEMM2: m_edge = hidden @ W2 + b2 + h_e  (epi rw [128..255])
  #pragma unroll
  for (int rt = 0; rt < RT; rt++) acc[rt] = (floatx4){0.f, 0.f, 0.f, 0.f};
  #pragma unroll
  for (int ks = 0; ks < 4; ks++) {
    short8 bfr = *(const short8*)(W2p + (((size_t)wave * 4 + ks) * 64 + lane) * 8);
    #pragma unroll
    for (int rt = 0; rt < RT; rt++) {
      short8 a = *(const short8*)(&Zt[(rt * 16 + colq) * SK + ks * 32 + quad * 8]);
      acc[rt] = __builtin_amdgcn_mfma_f32_16x16x32_bf16(a, bfr, acc[rt], 0, 0, 0);
    }
  }
  {
    int col = wave * 16 + colq;
    float bv = b2f(b2v[col]);
    #pragma unroll
    for (int rt = 0; rt < RT; rt++)
      #pragma unroll
      for (int r = 0; r < 4; r++) {
        int lrow = rt * 16 + quad * 4 + r;
        float v = acc[rt][r] + bv + b2f(Zt[lrow * SK + 128 + col]);
        Zt[lrow * SK + 128 + col] = __float2bfloat16(v);
      }
  }
  __syncthreads();

  // h_edges out (needed by layer 1) + dst-segment aggregation
  #pragma unroll
  for (int i = tid; i < BM * 16; i += 512) {
    int row = i >> 4, seg = i & 15;
    int gr = row0 + row;
    if (gr < M)
      *(uint4*)(outp + (size_t)gr * HDIM + seg * 8) = *(const uint4*)(&Zt[row * SK + 128 + seg * 8]);
  }
  {
    int col = tid & 127;
    int q4 = tid >> 7;
    int rbeg = q4 * 16, rend = rbeg + 16;
    float s = 0.f;
    int runDst = dstLds[rbeg];
    bool touchStart = true;
    for (int r = rbeg; r < rend; r++) {
      int d = dstLds[r];
      if (d != runDst) {
        if (runDst >= 0) {
          float* mp = &mnode[(size_t)runDst * HDIM + col];
          if (touchStart) atomicAdd(mp, s); else *mp = s;
        }
        runDst = d; s = 0.f; touchStart = false;
      }
      s += b2f(Zt[r * SK + 128 + col]);
    }
    if (runDst >= 0) atomicAdd(&mnode[(size_t)runDst * HDIM + col], s);
  }
}

// ----------------------- fused node update + fusion MLP (+ next-layer Y emit)
// 512 threads, 2x4 wave grid (round-5 win).
__global__ void __launch_bounds__(512) node_kernel(
    const bf16* __restrict__ h_nodes, float* __restrict__ mnode,
    const bf16* __restrict__ nuW1, const bf16* __restrict__ nuB1,
    const bf16* __restrict__ nuW2, const bf16* __restrict__ nuB2,
    const bf16* __restrict__ fuW1, const bf16* __restrict__ fuB1,
    const bf16* __restrict__ fuW2, const bf16* __restrict__ fuB2,
    const bf16* __restrict__ yW1a, const bf16* __restrict__ yW1b,
    bf16* __restrict__ ysA, bf16* __restrict__ ysB,
    bf16* __restrict__ outp, int M) {
  constexpr int BM = 64, SK = 272;
  __shared__ bf16 Zt[BM * SK];
  const int tid = threadIdx.x;
  const int lane = tid & 63, wave = tid >> 6, colq = lane & 15, quad = lane >> 4;
  const int wr = wave >> 2, wc = wave & 3;   // 2 row-groups x 4 col-groups
  const int row0 = blockIdx.x * BM;
  {
    int row = tid >> 3, sub = tid & 7;
    int gr = row0 + row;
    bool ok = gr < M;
    float4 z4 = {0.f, 0.f, 0.f, 0.f};
    #pragma unroll
    for (int j = 0; j < 4; j++) {
      int c = j * 8 + sub;
      int part = c >> 4, seg = c & 15;
      if (part == 0) {
        uint4 v = {0u, 0u, 0u, 0u};
        if (ok) v = *(const uint4*)(h_nodes + (size_t)gr * HDIM + seg * 8);
        *(uint4*)(&Zt[row * SK + seg * 8]) = v;
      } else {
        short8 o = {0, 0, 0, 0, 0, 0, 0, 0};
        if (ok) {
          float* mp = mnode + (size_t)gr * HDIM + seg * 8;
          #pragma unroll
          for (int k = 0; k < 8; k++) o[k] = f2s(mp[k]);
          if (yW1a) { *(float4*)(mp) = z4; *(float4*)(mp + 4) = z4; }
        }
        *(short8*)(&Zt[row * SK + 128 + seg * 8]) = o;
      }
    }
  }
  __syncthreads();

  floatx4 acc[2][2];
  // ---- GEMM1: nuW1, K=256
  #pragma unroll
  for (int rt = 0; rt < 2; rt++)
    #pragma unroll
    for (int c = 0; c < 2; c++) acc[rt][c] = (floatx4){0.f, 0.f, 0.f, 0.f};
  #pragma unroll
  for (int ks = 0; ks < 8; ks++) {
    short8 bfr0 = *(const short8*)(nuW1 + (((size_t)(wc * 2 + 0) * 8 + ks) * 64 + lane) * 8);
    short8 bfr1 = *(const short8*)(nuW1 + (((size_t)(wc * 2 + 1) * 8 + ks) * 64 + lane) * 8);
    #pragma unroll
    for (int rt = 0; rt < 2; rt++) {
      short8 a = *(const short8*)(&Zt[(wr * 32 + rt * 16 + colq) * SK + ks * 32 + quad * 8]);
      acc[rt][0] = __builtin_amdgcn_mfma_f32_16x16x32_bf16(a, bfr0, acc[rt][0], 0, 0, 0);
      acc[rt][1] = __builtin_amdgcn_mfma_f32_16x16x32_bf16(a, bfr1, acc[rt][1], 0, 0, 0);
    }
  }
  __syncthreads();
  #pragma unroll
  for (int c = 0; c < 2; c++) {
    int col = wc * 32 + c * 16 + colq;
    float bv = b2f(nuB1[col]);
    #pragma unroll
    for (int rt = 0; rt < 2; rt++)
      #pragma unroll
      for (int r = 0; r < 4; r++)
        Zt[(wr * 32 + rt * 16 + quad * 4 + r) * SK + 128 + col] =
            __float2bfloat16(fmaxf(acc[rt][c][r] + bv, 0.f));
  }
  __syncthreads();

  // ---- GEMM2: nuW2 (reads hidden at +128), residual h from Zt[0..127]
  #pragma unroll
  for (int rt = 0; rt < 2; rt++)
    #pragma unroll
    for (int c = 0; c < 2; c++) acc[rt][c] = (floatx4){0.f, 0.f, 0.f, 0.f};
  #pragma unroll
  for (int ks = 0; ks < 4; ks++) {
    short8 bfr0 = *(const short8*)(nuW2 + (((size_t)(wc * 2 + 0) * 4 + ks) * 64 + lane) * 8);
    short8 bfr1 = *(const short8*)(nuW2 + (((size_t)(wc * 2 + 1) * 4 + ks) * 64 + lane) * 8);
    #pragma unroll
    for (int rt = 0; rt < 2; rt++) {
      short8 a = *(const short8*)(&Zt[(wr * 32 + rt * 16 + colq) * SK + 128 + ks * 32 + quad * 8]);
      acc[rt][0] = __builtin_amdgcn_mfma_f32_16x16x32_bf16(a, bfr0, acc[rt][0], 0, 0, 0);
      acc[rt][1] = __builtin_amdgcn_mfma_f32_16x16x32_bf16(a, bfr1, acc[rt][1], 0, 0, 0);
    }
  }
  #pragma unroll
  for (int c = 0; c < 2; c++) {
    int col = wc * 32 + c * 16 + colq;
    float bv = b2f(nuB2[col]);
    #pragma unroll
    for (int rt = 0; rt < 2; rt++)
      #pragma unroll
      for (int r = 0; r < 4; r++) {
        int lrow = wr * 32 + rt * 16 + quad * 4 + r;
        float v = acc[rt][c][r] + bv + b2f(Zt[lrow * SK + col]);
        Zt[lrow * SK + col] = __float2bfloat16(v);
      }
  }
  __syncthreads();

  // ---- GEMM3: fuW1 (reads local at 0..127), hidden to +128
  #pragma unroll
  for (int rt = 0; rt < 2; rt++)
    #pragma unroll
    for (int c = 0; c < 2; c++) acc[rt][c] = (floatx4){0.f, 0.f, 0.f, 0.f};
  #pragma unroll
  for (int ks = 0; ks < 4; ks++) {
    short8 bfr0 = *(const short8*)(fuW1 + (((size_t)(wc * 2 + 0) * 4 + ks) * 64 + lane) * 8);
    short8 bfr1 = *(const short8*)(fuW1 + (((size_t)(wc * 2 + 1) * 4 + ks) * 64 + lane) * 8);
    #pragma unroll
    for (int rt = 0; rt < 2; rt++) {
      short8 a = *(const short8*)(&Zt[(wr * 32 + rt * 16 + colq) * SK + ks * 32 + quad * 8]);
      acc[rt][0] = __builtin_amdgcn_mfma_f32_16x16x32_bf16(a, bfr0, acc[rt][0], 0, 0, 0);
      acc[rt][1] = __builtin_amdgcn_mfma_f32_16x16x32_bf16(a, bfr1, acc[rt][1], 0, 0, 0);
    }
  }
  #pragma unroll
  for (int c = 0; c < 2; c++) {
    int col = wc * 32 + c * 16 + colq;
    float bv = b2f(fuB1[col]);
    #pragma unroll
    for (int rt = 0; rt < 2; rt++)
      #pragma unroll
      for (int r = 0; r < 4; r++)
        Zt[(wr * 32 + rt * 16 + quad * 4 + r) * SK + 128 + col] =
            __float2bfloat16(fmaxf(acc[rt][c][r] + bv, 0.f));
  }
  __syncthreads();

  // ---- GEMM4: fuW2 (reads +128), final h to 0..127
  #pragma unroll
  for (int rt = 0; rt < 2; rt++)
    #pragma unroll
    for (int c = 0; c < 2; c++) acc[rt][c] = (floatx4){0.f, 0.f, 0.f, 0.f};
  #pragma unroll
  for (int ks = 0; ks < 4; ks++) {
    short8 bfr0 = *(const short8*)(fuW2 + (((size_t)(wc * 2 + 0) * 4 + ks) * 64 + lane) * 8);
    short8 bfr1 = *(const short8*)(fuW2 + (((size_t)(wc * 2 + 1) * 4 + ks) * 64 + lane) * 8);
    #pragma unroll
    for (int rt = 0; rt < 2; rt++) {
      short8 a = *(const short8*)(&Zt[(wr * 32 + rt * 16 + colq) * SK + 128 + ks * 32 + quad * 8]);
      acc[rt][0] = __builtin_amdgcn_mfma_f32_16x16x32_bf16(a, bfr0, acc[rt][0], 0, 0, 0);
      acc[rt][1] = __builtin_amdgcn_mfma_f32_16x16x32_bf16(a, bfr1, acc[rt][1], 0, 0, 0);
    }
  }
  #pragma unroll
  for (int c = 0; c < 2; c++) {
    int col = wc * 32 + c * 16 + colq;
    float bv = b2f(fuB2[col]);
    #pragma unroll
    for (int rt = 0; rt < 2; rt++)
      #pragma unroll
      for (int r = 0; r < 4; r++) {
        int lrow = wr * 32 + rt * 16 + quad * 4 + r;
        Zt[lrow * SK + col] = __float2bfloat16(acc[rt][c][r] + bv);
      }
  }
  __syncthreads();
  // vectorized h_nodes write from Zt[0..127]
  for (int i = tid; i < BM * 16; i += 512) {
    int row = i >> 4, seg = i & 15;
    int gr = row0 + row;
    if (gr < M)
      *(uint4*)(outp + (size_t)gr * HDIM + seg * 8) = *(const uint4*)(&Zt[row * SK + seg * 8]);
  }
  if (!yW1a) return;

  #pragma unroll
  for (int which = 0; which < 2; which++) {
    const bf16* Wp = which ? yW1b : yW1a;
    bf16* outy = which ? ysB : ysA;
    #pragma unroll
    for (int rt = 0; rt < 2; rt++)
      #pragma unroll
      for (int c = 0; c < 2; c++) acc[rt][c] = (floatx4){0.f, 0.f, 0.f, 0.f};
    #pragma unroll
    for (int ks = 0; ks < 4; ks++) {
      short8 bfr0 = *(const short8*)(Wp + (((size_t)(wc * 2 + 0) * 4 + ks) * 64 + lane) * 8);
      short8 bfr1 = *(const short8*)(Wp + (((size_t)(wc * 2 + 1) * 4 + ks) * 64 + lane) * 8);
      #pragma unroll
      for (int rt = 0; rt < 2; rt++) {
        short8 a = *(const short8*)(&Zt[(wr * 32 + rt * 16 + colq) * SK + ks * 32 + quad * 8]);
        acc[rt][0] = __builtin_amdgcn_mfma_f32_16x16x32_bf16(a, bfr0, acc[rt][0], 0, 0, 0);
        acc[rt][1] = __builtin_amdgcn_mfma_f32_16x16x32_bf16(a, bfr1, acc[rt][1], 0, 0, 0);
      }
    }
    #pragma unroll
    for (int c = 0; c < 2; c++) {
      int col = wc * 32 + c * 16 + colq;
      #pragma unroll
      for (int rt = 0; rt < 2; rt++)
        #pragma unroll
        for (int r = 0; r < 4; r++)
          Zt[(wr * 32 + rt * 16 + quad * 4 + r) * SK + 128 + col] =
              __float2bfloat16(acc[rt][c][r]);
    }
    __syncthreads();
    for (int i = tid; i < BM * 16; i += 512) {
      int row = i >> 4, seg = i & 15;
      int gr = row0 + row;
      if (gr < M)
        *(uint4*)(outy + (size_t)gr * HDIM + seg * 8) = *(const uint4*)(&Zt[row * SK + 128 + seg * 8]);
    }
    __syncthreads();
  }
}

// --------------- typed encoder (type-sorted) + layer-0 Y emit (ee branch moved to eeeu)
__global__ void __launch_bounds__(512) enc_kernel(
    int ngrid64,
    const bf16* __restrict__ x, const bf16* __restrict__ pe,
    const int* __restrict__ perm, const int* __restrict__ ts,
    const bf16* __restrict__ encW1, const bf16* __restrict__ encB1,
    const bf16* __restrict__ encW2, const bf16* __restrict__ encB2,
    bf16* __restrict__ h_nodes,
    const bf16* __restrict__ yW1a, const bf16* __restrict__ yW1b,
    bf16* __restrict__ ysA, bf16* __restrict__ ysB) {
  constexpr int BM = 64, SKz = 40, HS = 144;
  __shared__ bf16 Zt[BM * SKz];
  __shared__ bf16 Hid[BM * HS];
  __shared__ int gIdx[BM];
  const int tid = threadIdx.x;
  const int lane = tid & 63, wave = tid >> 6, colq = lane & 15, quad = lane >> 4;
  const int wr = wave >> 2, wc = wave & 3;
  int t = blockIdx.x / ngrid64;
  int bx = blockIdx.x - t * ngrid64;
  int rs = ts[t], re = ts[t + 1];
  int row0 = rs + bx * BM;
  if (row0 >= re) return;
  for (int i = tid; i < BM; i += 512) gIdx[i] = (row0 + i < re) ? perm[row0 + i] : -1;
  __syncthreads();
  for (int i = tid; i < BM * 32; i += 512) {
    int row = i >> 5, k = i & 31;
    int g = gIdx[row];
    bf16 v = __float2bfloat16(0.f);
    if (g >= 0 && k < 14) v = (k < 6) ? x[(size_t)g * 6 + k] : pe[(size_t)g * 8 + (k - 6)];
    Zt[row * SKz + k] = v;
  }
  __syncthreads();
  const bf16* W1t = encW1 + (size_t)t * 4096;
  const bf16* W2t = encW2 + (size_t)t * 16384;
  floatx4 acc[2][2];
  #pragma unroll
  for (int rt = 0; rt < 2; rt++)
    #pragma unroll
    for (int c = 0; c < 2; c++) acc[rt][c] = (floatx4){0.f, 0.f, 0.f, 0.f};
  {
    short8 bfr0 = *(const short8*)(W1t + (((size_t)(wc * 2 + 0)) * 64 + lane) * 8);
    short8 bfr1 = *(const short8*)(W1t + (((size_t)(wc * 2 + 1)) * 64 + lane) * 8);
    #pragma unroll
    for (int rt = 0; rt < 2; rt++) {
      short8 a = *(const short8*)(&Zt[(wr * 32 + rt * 16 + colq) * SKz + quad * 8]);
      acc[rt][0] = __builtin_amdgcn_mfma_f32_16x16x32_bf16(a, bfr0, acc[rt][0], 0, 0, 0);
      acc[rt][1] = __builtin_amdgcn_mfma_f32_16x16x32_bf16(a, bfr1, acc[rt][1], 0, 0, 0);
    }
  }
  #pragma unroll
  for (int c = 0; c < 2; c++) {
    int col = wc * 32 + c * 16 + colq;
    float bv = b2f(encB1[t * HDIM + col]);
    #pragma unroll
    for (int rt = 0; rt < 2; rt++)
      #pragma unroll
      for (int r = 0; r < 4; r++)
        Hid[(wr * 32 + rt * 16 + quad * 4 + r) * HS + col] =
            __float2bfloat16(fmaxf(acc[rt][c][r] + bv, 0.f));
  }
  __syncthreads();
  floatx4 acc2[2][2];
  #pragma unroll
  for (int rt = 0; rt < 2; rt++)
    #pragma unroll
    for (int c = 0; c < 2; c++) acc2[rt][c] = (floatx4){0.f, 0.f, 0.f, 0.f};
  #pragma unroll
  for (int ks = 0; ks < 4; ks++) {
    short8 bfr0 = *(const short8*)(W2t + (((size_t)(wc * 2 + 0) * 4 + ks) * 64 + lane) * 8);
    short8 bfr1 = *(const short8*)(W2t + (((size_t)(wc * 2 + 1) * 4 + ks) * 64 + lane) * 8);
    #pragma unroll
    for (int rt = 0; rt < 2; rt++) {
      short8 a = *(const short8*)(&Hid[(wr * 32 + rt * 16 + colq) * HS + ks * 32 + quad * 8]);
      acc2[rt][0] = __builtin_amdgcn_mfma_f32_16x16x32_bf16(a, bfr0, acc2[rt][0], 0, 0, 0);
      acc2[rt][1] = __builtin_amdgcn_mfma_f32_16x16x32_bf16(a, bfr1, acc2[rt][1], 0, 0, 0);
    }
  }
  __syncthreads();   // all Hid reads done before overwrite with h
  #pragma unroll
  for (int c = 0; c < 2; c++) {
    int col = wc * 32 + c * 16 + colq;
    float bv = b2f(encB2[t * HDIM + col]);
    #pragma unroll
    for (int rt = 0; rt < 2; rt++)
      #pragma unroll
      for (int r = 0; r < 4; r++) {
        int row = wr * 32 + rt * 16 + quad * 4 + r;
        int g = gIdx[row];
        bf16 hb = __float2bfloat16(acc2[rt][c][r] + bv);
        Hid[row * HS + col] = hb;
        if (g >= 0) h_nodes[(size_t)g * HDIM + col] = hb;
      }
  }
  __syncthreads();

  // ---- layer-0 Y emit: Y = h @ yW1a / yW1b, scattered via gIdx
  #pragma unroll
  for (int which = 0; which < 2; which++) {
    const bf16* Wp = which ? yW1b : yW1a;
    bf16* outy = which ? ysB : ysA;
    floatx4 accy[2][2];
    #pragma unroll
    for (int rt = 0; rt < 2; rt++)
      #pragma unroll
      for (int c = 0; c < 2; c++) accy[rt][c] = (floatx4){0.f, 0.f, 0.f, 0.f};
    #pragma unroll
    for (int ks = 0; ks < 4; ks++) {
      short8 bfr0 = *(const short8*)(Wp + (((size_t)(wc * 2 + 0) * 4 + ks) * 64 + lane) * 8);
      short8 bfr1 = *(const short8*)(Wp + (((size_t)(wc * 2 + 1) * 4 + ks) * 64 + lane) * 8);
      #pragma unroll
      for (int rt = 0; rt < 2; rt++) {
        short8 a = *(const short8*)(&Hid[(wr * 32 + rt * 16 + colq) * HS + ks * 32 + quad * 8]);
        accy[rt][0] = __builtin_amdgcn_mfma_f32_16x16x32_bf16(a, bfr0, accy[rt][0], 0, 0, 0);
        accy[rt][1] = __builtin_amdgcn_mfma_f32_16x16x32_bf16(a, bfr1, accy[rt][1], 0, 0, 0);
      }
    }
    #pragma unroll
    for (int c = 0; c < 2; c++) {
      int col = wc * 32 + c * 16 + colq;
      #pragma unroll
      for (int rt = 0; rt < 2; rt++)
        #pragma unroll
        for (int r = 0; r < 4; r++) {
          int g = gIdx[wr * 32 + rt * 16 + quad * 4 + r];
          if (g >= 0) outy[(size_t)g * HDIM + col] = __float2bfloat16(accy[rt][c][r]);
        }
    }
  }
}

// -------------------------------------------------- typed decoder (type-sorted MFMA)
__global__ void __launch_bounds__(256) dec_kernel(
    const bf16* __restrict__ in0,
    const int* __restrict__ perm, const int* __restrict__ ts, const int* __restrict__ flagp,
    const bf16* __restrict__ W1p, const bf16* __restrict__ b1v,
    const bf16* __restrict__ W2p, const bf16* __restrict__ b2v,
    void* __restrict__ outp) {
  constexpr int BM = 64, RT = 4, SK = 144, HS = 144;
  int t = blockIdx.y;
  int rs = ts[t], re = ts[t + 1];
  int row0 = rs + blockIdx.x * BM;
  if (row0 >= re) return;
  __shared__ bf16 Zt[BM * SK];
  __shared__ bf16 Hid[BM * HS];
  __shared__ int gIdx[BM];
  const int tid = threadIdx.x;
  const int lane = tid & 63, wave = tid >> 6, colq = lane & 15, quad = lane >> 4;
  for (int i = tid; i < BM; i += 256) gIdx[i] = (row0 + i < re) ? perm[row0 + i] : -1;
  __syncthreads();
  {
    int row = tid >> 2, sub = tid & 3;
    int g = gIdx[row];
    #pragma unroll
    for (int j = 0; j < 4; j++) {
      int seg = j * 4 + sub;
      uint4 v = {0u, 0u, 0u, 0u};
      if (g >= 0) v = *(const uint4*)(in0 + (size_t)g * HDIM + seg * 8);
      *(uint4*)(&Zt[row * SK + seg * 8]) = v;
    }
  }
  __syncthreads();
  const bf16* W1t = W1p + (size_t)t * 16384;
  const bf16* W2t = W2p + (size_t)t * 16384;
  floatx4 acc[RT][2];
  #pragma unroll
  for (int rt = 0; rt < RT; rt++)
    #pragma unroll
    for (int c = 0; c < 2; c++) acc[rt][c] = (floatx4){0.f, 0.f, 0.f, 0.f};
  #pragma unroll
  for (int ks = 0; ks < 4; ks++) {
    short8 bfr0 = *(const short8*)(W1t + (((size_t)(wave * 2 + 0) * 4 + ks) * 64 + lane) * 8);
    short8 bfr1 = *(const short8*)(W1t + (((size_t)(wave * 2 + 1) * 4 + ks) * 64 + lane) * 8);
    #pragma unroll
    for (int rt = 0; rt < RT; rt++) {
      short8 a = *(const short8*)(&Zt[(rt * 16 + colq) * SK + ks * 32 + quad * 8]);
      acc[rt][0] = __builtin_amdgcn_mfma_f32_16x16x32_bf16(a, bfr0, acc[rt][0], 0, 0, 0);
      acc[rt][1] = __builtin_amdgcn_mfma_f32_16x16x32_bf16(a, bfr1, acc[rt][1], 0, 0, 0);
    }
  }
  #pragma unroll
  for (int c = 0; c < 2; c++) {
    int col = wave * 32 + c * 16 + colq;
    float bv = b2f(b1v[t * HDIM + col]);
    #pragma unroll
    for (int rt = 0; rt < RT; rt++)
      #pragma unroll
      for (int r = 0; r < 4; r++)
        Hid[(rt * 16 + quad * 4 + r) * HS + col] =
            __float2bfloat16(fmaxf(acc[rt][c][r] + bv, 0.f));
  }
  __syncthreads();
  floatx4 acc2[RT];
  #pragma unroll
  for (int rt = 0; rt < RT; rt++) acc2[rt] = (floatx4){0.f, 0.f, 0.f, 0.f};
  #pragma unroll
  for (int ks = 0; ks < 4; ks++) {
    short8 bfr0 = *(const short8*)(W2t + (((size_t)0 * 4 + ks) * 64 + lane) * 8);
    #pragma unroll
    for (int rt = 0; rt < RT; rt++) {
      short8 a = *(const short8*)(&Hid[(rt * 16 + colq) * HS + ks * 32 + quad * 8]);
      acc2[rt] = __builtin_amdgcn_mfma_f32_16x16x32_bf16(a, bfr0, acc2[rt], 0, 0, 0);
    }
  }
  if (wave == 0 && colq < 4) {
    int isBf = flagp[0];
    float bv = b2f(b2v[t * 4 + colq]);
    #pragma unroll
    for (int rt = 0; rt < RT; rt++)
      #pragma unroll
      for (int r = 0; r < 4; r++) {
        int g = gIdx[rt * 16 + quad * 4 + r];
        if (g >= 0) {
          float v = acc2[rt][r] + bv;
          if (isBf) ((bf16*)outp)[(size_t)g * 4 + colq] = __float2bfloat16(v);
          else      ((float*)outp)[(size_t)g * 4 + colq] = v;
        }
      }
  }
}

// ---------------------------------------------------------------- launcher
extern "C" void kernel_launch(void* const* d_in, const int* in_sizes, int n_in,
                              void* d_out, int out_size, void* d_ws, size_t ws_size,
                              hipStream_t stream) {
  const int* edge_index = (const int*)d_in[27];
  const int* node_types = (const int*)d_in[28];
  const int N = in_sizes[28];
  const int E = in_sizes[2] / 4;
  const int L = in_sizes[12] / HDIM;
  const int* srcI = edge_index;
  const int* dstI = edge_index + E;

  CanonDesc cd;
  int total = 0;
  for (int i = 0; i < NCANON; i++) { cd.src[i] = d_in[i]; cd.prefix[i] = total; total += in_sizes[i]; }
  cd.prefix[NCANON] = total;

  char* wsb = (char*)d_ws;
  size_t off = 0;
  auto alloc = [&](size_t bytes) -> void* {
    void* p = wsb + off;
    off += (bytes + 255) & ~(size_t)255;
    return p;
  };
  int*  flag      = (int*)alloc(256);
  bf16* arena     = (bf16*)alloc((size_t)total * 2);
  bf16* h_nodes   = (bf16*)alloc((size_t)N * HDIM * 2);
  bf16* h_edges   = (bf16*)alloc((size_t)E * HDIM * 2);
  bf16* ysrcb     = (bf16*)alloc((size_t)N * HDIM * 2);
  bf16* ydstb     = (bf16*)alloc((size_t)N * HDIM * 2);
  bf16* eaS       = (bf16*)alloc((size_t)E * 4 * 2);
  // m_node placed adjacent to counts/cursor so canon's tail blocks zero all three
  float* m_node   = (float*)alloc((size_t)N * HDIM * 4);
  int* counts     = (int*)alloc((size_t)N * 4);
  int* cursor     = (int*)alloc((size_t)N * 4);
  int* row_start  = (int*)alloc((size_t)(N + 1) * 4);
  int* bsum       = (int*)alloc(260 * 4);
  int* srcS       = (int*)alloc((size_t)E * 4);
  int* dstS       = (int*)alloc((size_t)E * 4);
  int* tsArr      = (int*)alloc(64);
  int* permT      = (int*)alloc((size_t)N * 4);
  bf16* eeW1p  = (bf16*)alloc(4096 * 2);
  bf16* eeW2p  = (bf16*)alloc(16384 * 2);
  bf16* encW1p = (bf16*)alloc(3 * 4096 * 2);
  bf16* encW2p = (bf16*)alloc(3 * 16384 * 2);
  bf16* decW1p = (bf16*)alloc(3 * 16384 * 2);
  bf16* decW2p = (bf16*)alloc(3 * 16384 * 2);
  bf16* euW1a  = (bf16*)alloc((size_t)L * 16384 * 2);
  bf16* euW1b  = (bf16*)alloc((size_t)L * 16384 * 2);
  bf16* euW1c  = (bf16*)alloc((size_t)L * 16384 * 2);
  bf16* euW2p  = (bf16*)alloc((size_t)L * 16384 * 2);
  bf16* nuW1p  = (bf16*)alloc((size_t)L * 32768 * 2);
  bf16* nuW2p  = (bf16*)alloc((size_t)L * 16384 * 2);
  bf16* fuW1p  = (bf16*)alloc((size_t)L * 16384 * 2);
  bf16* fuW2p  = (bf16*)alloc((size_t)L * 16384 * 2);

  const bf16* cX     = arena + cd.prefix[0];
  const bf16* cPE    = arena + cd.prefix[1];
  const bf16* cEA    = arena + cd.prefix[2];
  const bf16* cEncW1 = arena + cd.prefix[3];
  const bf16* cEncB1 = arena + cd.prefix[4];
  const bf16* cEncW2 = arena + cd.prefix[5];
  const bf16* cEncB2 = arena + cd.prefix[6];
  const bf16* cEeW1  = arena + cd.prefix[7];
  const bf16* cEeB1  = arena + cd.prefix[8];
  const bf16* cEeW2  = arena + cd.prefix[9];
  const bf16* cEeB2  = arena + cd.prefix[10];
  const bf16* cEuW1  = arena + cd.prefix[11];
  const bf16* cEuB1  = arena + cd.prefix[12];
  const bf16* cEuW2  = arena + cd.prefix[13];
  const bf16* cEuB2  = arena + cd.prefix[14];
  const bf16* cNuW1  = arena + cd.prefix[15];
  const bf16* cNuB1  = arena + cd.prefix[16];
  const bf16* cNuW2  = arena + cd.prefix[17];
  const bf16* cNuB2  = arena + cd.prefix[18];
  const bf16* cFuW1  = arena + cd.prefix[19];
  const bf16* cFuB1  = arena + cd.prefix[20];
  const bf16* cFuW2  = arena + cd.prefix[21];
  const bf16* cFuB2  = arena + cd.prefix[22];
  const bf16* cDecW1 = arena + cd.prefix[23];
  const bf16* cDecB1 = arena + cd.prefix[24];
  const bf16* cDecW2 = arena + cd.prefix[25];
  const bf16* cDecB2 = arena + cd.prefix[26];

  // canon (+ zero m_node/counts/cursor, contiguous 256-aligned region)
  int canonBlocks = (total + 255) / 256;
  size_t zbytes = (size_t)((char*)cursor - (char*)m_node) + (size_t)N * 4;
  int zquads = (int)(zbytes / 16);
  int zBlocks = (zquads + 255) / 256;
  canon_kernel<<<canonBlocks + zBlocks, 256, 0, stream>>>(
      cd, (const unsigned short*)d_in[0], flag, arena, total, canonBlocks,
      (uint4*)m_node, zquads);

  // hist + tsort (one dispatch, 1024 threads)
  int hb = (E + 1023) / 1024;
  hist_tsort_kernel<<<hb + 1, 1024, 0, stream>>>(dstI, counts, E, hb,
                                                 node_types, tsArr, permT, N);

  PackJobs PJ;
  int nj = 0;
  PJ.j[nj++] = {cEeW1, eeW1p, 4, 1, 128};
  PJ.j[nj++] = {cEeW2, eeW2p, 128, 4, 128};
  for (int l = 0; l < L; l++) {
    const bf16* w1 = cEuW1 + (size_t)l * 384 * HDIM;
    PJ.j[nj++] = {w1,                 euW1a + (size_t)l * 16384, 128, 4, 128};
    PJ.j[nj++] = {w1 + 128 * HDIM,    euW1b + (size_t)l * 16384, 128, 4, 128};
    PJ.j[nj++] = {w1 + 256 * HDIM,    euW1c + (size_t)l * 16384, 128, 4, 128};
    PJ.j[nj++] = {cEuW2 + (size_t)l * HDIM * HDIM, euW2p + (size_t)l * 16384, 128, 4, 128};
    PJ.j[nj++] = {cNuW1 + (size_t)l * 256 * HDIM,  nuW1p + (size_t)l * 32768, 256, 8, 128};
    PJ.j[nj++] = {cNuW2 + (size_t)l * HDIM * HDIM, nuW2p + (size_t)l * 16384, 128, 4, 128};
    PJ.j[nj++] = {cFuW1 + (size_t)l * HDIM * HDIM, fuW1p + (size_t)l * 16384, 128, 4, 128};
    PJ.j[nj++] = {cFuW2 + (size_t)l * HDIM * HDIM, fuW2p + (size_t)l * 16384, 128, 4, 128};
  }
  for (int t = 0; t < 3; t++) {
    PJ.j[nj++] = {cEncW1 + (size_t)t * 14 * HDIM,   encW1p + (size_t)t * 4096, 14, 1, 128};
    PJ.j[nj++] = {cEncW2 + (size_t)t * HDIM * HDIM, encW2p + (size_t)t * 16384, 128, 4, 128};
    PJ.j[nj++] = {cDecW1 + (size_t)t * HDIM * HDIM, decW1p + (size_t)t * 16384, 128, 4, 128};
    PJ.j[nj++] = {cDecW2 + (size_t)t * HDIM * 4,    decW2p + (size_t)t * 16384, 128, 4, 4};
  }
  pack_all_kernel<<<dim3(16, nj), 256, 0, stream>>>(PJ);

  int nb = (N + 255) / 256;
  scan1_kernel<<<nb, 256, 0, stream>>>(counts, bsum, N);
  scan2_kernel<<<1, 64, 0, stream>>>(bsum, nb);
  scan3_kernel<<<nb, 256, 0, stream>>>(counts, bsum, row_start, N, nb);
  scatter_kernel<<<(E + 255) / 256, 256, 0, stream>>>(srcI, dstI, row_start, cursor,
                                                      cEA, eaS, srcS, dstS, E);

  int ngrid64  = (N + 63) / 64;
  int egrid64  = (E + 63) / 64;

  // typed encoder + layer-0 Y emit (must precede eeeu: produces ysrcb/ydstb)
  enc_kernel<<<3 * ngrid64, 512, 0, stream>>>(
      ngrid64, cX, cPE, permT, tsArr, encW1p, cEncB1, encW2p, cEncB2, h_nodes,
      euW1a, euW1b, ysrcb, ydstb);

  // fused edge-encoder + layer-0 edge-update + aggregation
  eeeu_kernel<<<egrid64, 512, 0, stream>>>(
      eaS, eeW1p, cEeB1, eeW2p, cEeB2,
      ysrcb, ydstb, srcS, dstS,
      euW1c, cEuB1, euW2p, cEuB2, h_edges, m_node, E);

  for (int l = 0; l < L; l++) {
    if (l > 0) {
      if (l + 1 < L) {
        eu_kernel<true><<<egrid64, 512, 0, stream>>>(
            h_edges, ysrcb, ydstb, srcS, dstS,
            euW1c + (size_t)l * 16384, cEuB1 + l * HDIM,
            euW2p + (size_t)l * 16384, cEuB2 + l * HDIM, h_edges, m_node, E);
      } else {
        eu_kernel<false><<<egrid64, 512, 0, stream>>>(
            h_edges, ysrcb, ydstb, srcS, dstS,
            euW1c + (size_t)l * 16384, cEuB1 + l * HDIM,
            euW2p + (size_t)l * 16384, cEuB2 + l * HDIM, h_edges, m_node, E);
      }
    }
    bool hasNext = (l + 1 < L);
    node_kernel<<<ngrid64, 512, 0, stream>>>(
        h_nodes, m_node,
        nuW1p + (size_t)l * 32768, cNuB1 + l * HDIM,
        nuW2p + (size_t)l * 16384, cNuB2 + l * HDIM,
        fuW1p + (size_t)l * 16384, cFuB1 + l * HDIM,
        fuW2p + (size_t)l * 16384, cFuB2 + l * HDIM,
        hasNext ? euW1a + (size_t)(l + 1) * 16384 : nullptr,
        hasNext ? euW1b + (size_t)(l + 1) * 16384 : nullptr,
        ysrcb, ydstb, h_nodes, N);
  }

  dec_kernel<<<dim3(ngrid64, 3), 256, 0, stream>>>(
      h_nodes, permT, tsArr, flag, decW1p, cDecB1, decW2p, cDecB2, d_out);
  (void)n_in; (void)ws_size;
}